// Round 1
// baseline (1992.211 us; speedup 1.0000x reference)
//
#include <hip/hip_runtime.h>

#define N_NODES 50000

// ---------------- index-width detection (int64 vs int32 edge_index) --------
__global__ void k_detect(const void* ei, int* flag) {
    // 1024 threads, 1 block. Interpret first 1024 words as int64.
    // Genuine int64 node ids are in [0, N_NODES); int32 data reinterpreted
    // as int64 combines two ids -> value >= 2^32 (hi word nonzero) w.h.p.
    __shared__ int bad;
    if (threadIdx.x == 0) bad = 0;
    __syncthreads();
    long long v = ((const long long*)ei)[threadIdx.x];
    if (v < 0 || v >= N_NODES) atomicOr(&bad, 1);
    __syncthreads();
    if (threadIdx.x == 0) *flag = bad ? 0 : 1;
}

__device__ __forceinline__ int eload(const void* ei, int idx, int is64) {
    return is64 ? (int)((const long long*)ei)[idx] : ((const int*)ei)[idx];
}

// ---------------- degree / normalization ----------------
__global__ void k_deg_init(float* degf, int n) {
    int i = blockIdx.x * blockDim.x + threadIdx.x;
    if (i < n) degf[i] = 1.0f;   // self-loop
}

__global__ void k_deg_count(const void* ei, const int* flag, float* degf, int e) {
    int i = blockIdx.x * blockDim.x + threadIdx.x;
    if (i >= e) return;
    int is64 = *flag;
    int d = eload(ei, e + i, is64);   // dst row starts at element e
    atomicAdd(&degf[d], 1.0f);
}

__global__ void k_dinv(const float* degf, float* dinv, int n) {
    int i = blockIdx.x * blockDim.x + threadIdx.x;
    if (i < n) dinv[i] = rsqrtf(degf[i]);   // deg >= 1 always (self-loop)
}

// ---------------- self-loop init (+optional bias) ----------------
__global__ void k_self_init(const float* __restrict__ h, const float* __restrict__ dinv,
                            const float* __restrict__ bias, float* __restrict__ out,
                            int n, int f) {
    int idx = blockIdx.x * blockDim.x + threadIdx.x;
    if (idx >= n * f) return;
    int i = idx / f;
    int j = idx - i * f;
    float d = dinv[i];
    float v = d * d * h[idx];
    if (bias) v += bias[j];
    out[idx] = v;
}

// ---------------- edge scatter-aggregation (atomic) ----------------
// F = 128: 2 edges per 256-thread block per iter, 4 iters -> 8 edges/block
__global__ void k_edge_agg128(const void* ei, const int* flag,
                              const float* __restrict__ dinv,
                              const float* __restrict__ h,
                              float* out, int e) {
    int is64 = *flag;
    int fidx = threadIdx.x & 127;
    int sub  = threadIdx.x >> 7;   // 0..1
    #pragma unroll
    for (int it = 0; it < 4; ++it) {
        int eidx = blockIdx.x * 8 + it * 2 + sub;
        if (eidx >= e) return;
        int s = eload(ei, eidx, is64);
        int d = eload(ei, e + eidx, is64);
        float norm = dinv[s] * dinv[d];
        atomicAdd(&out[d * 128 + fidx], norm * h[s * 128 + fidx]);
    }
}

// F = 250: 1 edge per 256-thread block per iter (250 active lanes), 4 iters
__global__ void k_edge_agg250(const void* ei, const int* flag,
                              const float* __restrict__ dinv,
                              const float* __restrict__ h,
                              float* out, int e) {
    int is64 = *flag;
    int fidx = threadIdx.x;
    #pragma unroll
    for (int it = 0; it < 4; ++it) {
        int eidx = blockIdx.x * 4 + it;
        if (eidx >= e) return;
        if (fidx < 250) {
            int s = eload(ei, eidx, is64);
            int d = eload(ei, e + eidx, is64);
            float norm = dinv[s] * dinv[d];
            atomicAdd(&out[d * 250 + fidx], norm * h[s * 250 + fidx]);
        }
    }
}

// ---------------- tiled f32 GEMM: C = A[MxK] * B[KxN] (+bias, relu) -------
#define GBM 128
#define GBN 64
#define GBK 32

__global__ __launch_bounds__(256)
void k_gemm(const float* __restrict__ A, const float* __restrict__ B,
            const float* __restrict__ bias, float* __restrict__ C,
            int M, int N, int K, int relu) {
    __shared__ float As[GBK][GBM + 4];   // A tile, transposed
    __shared__ float Bs[GBK][GBN + 4];
    const int tid  = threadIdx.x;
    const int brow = blockIdx.y * GBM;
    const int bcol = blockIdx.x * GBN;
    const int tr = (tid >> 4) * 8;   // 0..120
    const int tc = (tid & 15) * 4;   // 0..60
    float acc[8][4] = {};

    for (int k0 = 0; k0 < K; k0 += GBK) {
        // A tile: GBM x GBK = 4096 elems, 16/thread, coalesced rows
        #pragma unroll
        for (int i = 0; i < 16; ++i) {
            int idx = tid + i * 256;
            int r = idx >> 5;        // / GBK
            int c = idx & 31;
            int gr = brow + r;
            As[c][r] = (gr < M) ? A[(long long)gr * K + (k0 + c)] : 0.0f;
        }
        // B tile: GBK x GBN = 2048 elems, 8/thread
        #pragma unroll
        for (int i = 0; i < 8; ++i) {
            int idx = tid + i * 256;
            int r = idx >> 6;
            int c = idx & 63;
            int gc = bcol + c;
            Bs[r][c] = (gc < N) ? B[(long long)(k0 + r) * N + gc] : 0.0f;
        }
        __syncthreads();
        #pragma unroll
        for (int kk = 0; kk < GBK; ++kk) {
            float4 b4 = *(const float4*)&Bs[kk][tc];
            float4 a0 = *(const float4*)&As[kk][tr];
            float4 a1 = *(const float4*)&As[kk][tr + 4];
            float a[8] = {a0.x, a0.y, a0.z, a0.w, a1.x, a1.y, a1.z, a1.w};
            float b[4] = {b4.x, b4.y, b4.z, b4.w};
            #pragma unroll
            for (int ii = 0; ii < 8; ++ii)
                #pragma unroll
                for (int jj = 0; jj < 4; ++jj)
                    acc[ii][jj] = fmaf(a[ii], b[jj], acc[ii][jj]);
        }
        __syncthreads();
    }

    #pragma unroll
    for (int ii = 0; ii < 8; ++ii) {
        int gr = brow + tr + ii;
        if (gr >= M) continue;
        #pragma unroll
        for (int jj = 0; jj < 4; ++jj) {
            int gc = bcol + tc + jj;
            if (gc >= N) continue;
            float v = acc[ii][jj];
            if (bias) v += bias[gc];
            if (relu) v = fmaxf(v, 0.0f);
            C[(long long)gr * N + gc] = v;
        }
    }
}

// ---------------- final relu ----------------
__global__ void k_relu(float* p, int n) {
    int i = blockIdx.x * blockDim.x + threadIdx.x;
    if (i < n) p[i] = fmaxf(p[i], 0.0f);
}

extern "C" void kernel_launch(void* const* d_in, const int* in_sizes, int n_in,
                              void* d_out, int out_size, void* d_ws, size_t ws_size,
                              hipStream_t stream) {
    const float* x  = (const float*)d_in[0];
    const void*  ei = d_in[1];
    const float* W1 = (const float*)d_in[2];
    const float* b1 = (const float*)d_in[3];
    const float* W2 = (const float*)d_in[4];
    const float* b2 = (const float*)d_in[5];
    float* out = (float*)d_out;

    const int N = N_NODES;
    const int E = in_sizes[1] / 2;

    // workspace layout
    char* base = (char*)d_ws;
    int*   flag = (int*)base;
    float* degf = (float*)(base + 256);
    float* dinv = degf + 51200;
    float* aggx = dinv + 51200;                    // [N,128]
    float* h1   = aggx + (size_t)N * 128;          // [N,512]
    float* t    = h1   + (size_t)N * 512;          // [N,250]

    // 1. detect index width, compute deg^-1/2
    k_detect<<<1, 1024, 0, stream>>>(ei, flag);
    k_deg_init<<<(N + 255) / 256, 256, 0, stream>>>(degf, N);
    k_deg_count<<<(E + 255) / 256, 256, 0, stream>>>(ei, flag, degf, E);
    k_dinv<<<(N + 255) / 256, 256, 0, stream>>>(degf, dinv, N);

    // 2. layer 1 aggregation on raw x (128 features): aggx = A_norm @ x
    k_self_init<<<(N * 128 + 255) / 256, 256, 0, stream>>>(x, dinv, nullptr, aggx, N, 128);
    k_edge_agg128<<<(E + 7) / 8, 256, 0, stream>>>(ei, flag, dinv, x, aggx, E);

    // 3. h1 = relu(aggx @ W1 + b1)   [50000,512]
    {
        dim3 grid((512 + GBN - 1) / GBN, (N + GBM - 1) / GBM);
        k_gemm<<<grid, 256, 0, stream>>>(aggx, W1, b1, h1, N, 512, 128, 1);
    }

    // 4. t = h1 @ W2                 [50000,250]
    {
        dim3 grid((250 + GBN - 1) / GBN, (N + GBM - 1) / GBM);
        k_gemm<<<grid, 256, 0, stream>>>(h1, W2, nullptr, t, N, 250, 512, 0);
    }

    // 5. layer 2 aggregation on t (250 features) into out, + b2, then relu
    k_self_init<<<(N * 250 + 255) / 256, 256, 0, stream>>>(t, dinv, b2, out, N, 250);
    k_edge_agg250<<<(E + 3) / 4, 256, 0, stream>>>(ei, flag, dinv, t, out, E);
    k_relu<<<(N * 250 + 255) / 256, 256, 0, stream>>>(out, N * 250);
}

// Round 2
// 1101.561 us; speedup vs baseline: 1.8085x; 1.8085x over previous
//
#include <hip/hip_runtime.h>

#define N_NODES 50000

// ---------------- index-width detection (int64 vs int32 edge_index) --------
__global__ void k_detect(const void* ei, int* flag) {
    __shared__ int bad;
    if (threadIdx.x == 0) bad = 0;
    __syncthreads();
    long long v = ((const long long*)ei)[threadIdx.x];
    if (v < 0 || v >= N_NODES) atomicOr(&bad, 1);
    __syncthreads();
    if (threadIdx.x == 0) *flag = bad ? 0 : 1;
}

__device__ __forceinline__ int eload(const void* ei, int idx, int is64) {
    return is64 ? (int)((const long long*)ei)[idx] : ((const int*)ei)[idx];
}

// ---------------- CSR build ----------------
__global__ void k_zero_int(int* p, int n) {
    int i = blockIdx.x * blockDim.x + threadIdx.x;
    if (i < n) p[i] = 0;
}

__global__ void k_hist(const void* ei, const int* flag, int* deg, int e) {
    int i = blockIdx.x * blockDim.x + threadIdx.x;
    if (i >= e) return;
    int is64 = *flag;
    int d = eload(ei, e + i, is64);
    atomicAdd(&deg[d], 1);
}

__global__ void k_dinv(const int* deg, float* dinv, int n) {
    int i = blockIdx.x * blockDim.x + threadIdx.x;
    if (i < n) dinv[i] = rsqrtf((float)(deg[i] + 1));  // +1 self-loop
}

// single-block chunked inclusive scan -> rowptr[0..n], 1024 threads
__global__ void k_scan(const int* deg, int* rowptr, int n) {
    __shared__ int wsum[16];
    __shared__ int carry;
    const int tid = threadIdx.x;
    const int lane = tid & 63, wid = tid >> 6;   // 16 waves
    if (tid == 0) { carry = 0; rowptr[0] = 0; }
    __syncthreads();
    for (int base = 0; base < n; base += 1024) {
        int v = (base + tid < n) ? deg[base + tid] : 0;
        int x = v;
        #pragma unroll
        for (int off = 1; off < 64; off <<= 1) {
            int y = __shfl_up(x, off, 64);
            if (lane >= off) x += y;
        }
        if (lane == 63) wsum[wid] = x;
        __syncthreads();
        if (wid == 0) {
            int s = (lane < 16) ? wsum[lane] : 0;
            #pragma unroll
            for (int off = 1; off < 16; off <<= 1) {
                int y = __shfl_up(s, off, 64);
                if (lane >= off) s += y;
            }
            if (lane < 16) wsum[lane] = s;
        }
        __syncthreads();
        int offset = carry + (wid > 0 ? wsum[wid - 1] : 0);
        if (base + tid < n) rowptr[base + tid + 1] = offset + x;
        __syncthreads();
        if (tid == 0) carry += wsum[15];
        __syncthreads();
    }
}

__global__ void k_copy_int(const int* a, int* b, int n) {
    int i = blockIdx.x * blockDim.x + threadIdx.x;
    if (i < n) b[i] = a[i];
}

__global__ void k_fill(const void* ei, const int* flag, int* cur, int* adj, int e) {
    int i = blockIdx.x * blockDim.x + threadIdx.x;
    if (i >= e) return;
    int is64 = *flag;
    int s = eload(ei, i, is64);
    int d = eload(ei, e + i, is64);
    int pos = atomicAdd(&cur[d], 1);
    adj[pos] = s;
}

// ---------------- pull aggregation, layer 1 (F=128, unscaled x) ----------
// agg1[i,f] = dinv[i] * ( dinv[i]*x[i,f] + sum_s dinv[s]*x[s,f] )
__global__ __launch_bounds__(256)
void k_pull128(const int* __restrict__ rowptr, const int* __restrict__ adj,
               const float* __restrict__ dinv, const float* __restrict__ x,
               float* __restrict__ out, int n) {
    const int i = blockIdx.x * 2 + (threadIdx.x >> 7);
    if (i >= n) return;
    const int f = threadIdx.x & 127;
    const float di = dinv[i];
    float acc = di * x[(size_t)i * 128 + f];
    int j = rowptr[i];
    const int end = rowptr[i + 1];
    for (; j + 4 <= end; j += 4) {
        int s0 = adj[j], s1 = adj[j + 1], s2 = adj[j + 2], s3 = adj[j + 3];
        float w0 = dinv[s0], w1 = dinv[s1], w2 = dinv[s2], w3 = dinv[s3];
        acc += w0 * x[(size_t)s0 * 128 + f];
        acc += w1 * x[(size_t)s1 * 128 + f];
        acc += w2 * x[(size_t)s2 * 128 + f];
        acc += w3 * x[(size_t)s3 * 128 + f];
    }
    for (; j < end; ++j) {
        int s = adj[j];
        acc += dinv[s] * x[(size_t)s * 128 + f];
    }
    out[(size_t)i * 128 + f] = di * acc;
}

// ---------------- pull aggregation, layer 2 (F=250, t pre-scaled) --------
// out[i,f] = relu( dinv[i] * ( t[i,f] + sum_s t[s,f] ) + b[f] )
__global__ __launch_bounds__(256)
void k_pull250(const int* __restrict__ rowptr, const int* __restrict__ adj,
               const float* __restrict__ dinv, const float* __restrict__ t,
               const float* __restrict__ bias, float* __restrict__ out, int n) {
    const int i = blockIdx.x;
    const int f = threadIdx.x;
    if (i >= n || f >= 250) return;
    float acc = t[(size_t)i * 250 + f];
    int j = rowptr[i];
    const int end = rowptr[i + 1];
    for (; j + 4 <= end; j += 4) {
        int s0 = adj[j], s1 = adj[j + 1], s2 = adj[j + 2], s3 = adj[j + 3];
        acc += t[(size_t)s0 * 250 + f];
        acc += t[(size_t)s1 * 250 + f];
        acc += t[(size_t)s2 * 250 + f];
        acc += t[(size_t)s3 * 250 + f];
    }
    for (; j < end; ++j)
        acc += t[(size_t)adj[j] * 250 + f];
    float v = dinv[i] * acc + bias[f];
    out[(size_t)i * 250 + f] = fmaxf(v, 0.0f);
}

// ---------------- tiled f32 GEMM: C = A[MxK] * B[KxN] -------------------
// epilogue: optional row-scale (rscale[row]), bias, relu
#define GBM 128
#define GBN 64
#define GBK 32

__global__ __launch_bounds__(256)
void k_gemm(const float* __restrict__ A, const float* __restrict__ B,
            const float* __restrict__ bias, const float* __restrict__ rscale,
            float* __restrict__ C, int M, int N, int K, int relu) {
    __shared__ float As[GBK][GBM + 4];
    __shared__ float Bs[GBK][GBN + 4];
    const int tid  = threadIdx.x;
    const int brow = blockIdx.y * GBM;
    const int bcol = blockIdx.x * GBN;
    const int tr = (tid >> 4) * 8;
    const int tc = (tid & 15) * 4;
    float acc[8][4] = {};

    for (int k0 = 0; k0 < K; k0 += GBK) {
        #pragma unroll
        for (int i = 0; i < 16; ++i) {
            int idx = tid + i * 256;
            int r = idx >> 5;
            int c = idx & 31;
            int gr = brow + r;
            As[c][r] = (gr < M) ? A[(long long)gr * K + (k0 + c)] : 0.0f;
        }
        #pragma unroll
        for (int i = 0; i < 8; ++i) {
            int idx = tid + i * 256;
            int r = idx >> 6;
            int c = idx & 63;
            int gc = bcol + c;
            Bs[r][c] = (gc < N) ? B[(long long)(k0 + r) * N + gc] : 0.0f;
        }
        __syncthreads();
        #pragma unroll
        for (int kk = 0; kk < GBK; ++kk) {
            float4 b4 = *(const float4*)&Bs[kk][tc];
            float4 a0 = *(const float4*)&As[kk][tr];
            float4 a1 = *(const float4*)&As[kk][tr + 4];
            float a[8] = {a0.x, a0.y, a0.z, a0.w, a1.x, a1.y, a1.z, a1.w};
            float b[4] = {b4.x, b4.y, b4.z, b4.w};
            #pragma unroll
            for (int ii = 0; ii < 8; ++ii)
                #pragma unroll
                for (int jj = 0; jj < 4; ++jj)
                    acc[ii][jj] = fmaf(a[ii], b[jj], acc[ii][jj]);
        }
        __syncthreads();
    }

    #pragma unroll
    for (int ii = 0; ii < 8; ++ii) {
        int gr = brow + tr + ii;
        if (gr >= M) continue;
        float rs = rscale ? rscale[gr] : 1.0f;
        #pragma unroll
        for (int jj = 0; jj < 4; ++jj) {
            int gc = bcol + tc + jj;
            if (gc >= N) continue;
            float v = acc[ii][jj] * rs;
            if (bias) v += bias[gc];
            if (relu) v = fmaxf(v, 0.0f);
            C[(long long)gr * N + gc] = v;
        }
    }
}

extern "C" void kernel_launch(void* const* d_in, const int* in_sizes, int n_in,
                              void* d_out, int out_size, void* d_ws, size_t ws_size,
                              hipStream_t stream) {
    const float* x  = (const float*)d_in[0];
    const void*  ei = d_in[1];
    const float* W1 = (const float*)d_in[2];
    const float* b1 = (const float*)d_in[3];
    const float* W2 = (const float*)d_in[4];
    const float* b2 = (const float*)d_in[5];
    float* out = (float*)d_out;

    const int N = N_NODES;
    const int E = in_sizes[1] / 2;

    // workspace layout
    char* base = (char*)d_ws;
    int*   flag   = (int*)base;                       // 256 B slot
    int*   deg    = (int*)(base + 256);               // [51200]
    int*   rowptr = deg + 51200;                      // [51200] (needs N+1)
    int*   cur    = rowptr + 51200;                   // [51200]
    float* dinv   = (float*)(cur + 51200);            // [51200]
    int*   adj    = (int*)(dinv + 51200);             // [E]
    float* buf_t  = (float*)(adj + ((E + 63) & ~63)); // agg1 [N,128] then t [N,250]
    float* h1     = buf_t + (size_t)N * 250;          // [N,512]

    // 1. CSR build + normalization
    k_detect<<<1, 1024, 0, stream>>>(ei, flag);
    k_zero_int<<<(N + 255) / 256, 256, 0, stream>>>(deg, N);
    k_hist<<<(E + 255) / 256, 256, 0, stream>>>(ei, flag, deg, E);
    k_dinv<<<(N + 255) / 256, 256, 0, stream>>>(deg, dinv, N);
    k_scan<<<1, 1024, 0, stream>>>(deg, rowptr, N);
    k_copy_int<<<(N + 255) / 256, 256, 0, stream>>>(rowptr, cur, N);
    k_fill<<<(E + 255) / 256, 256, 0, stream>>>(ei, flag, cur, adj, E);

    // 2. layer 1 aggregation (pull): agg1 = A_norm @ x   [N,128]
    k_pull128<<<(N + 1) / 2, 256, 0, stream>>>(rowptr, adj, dinv, x, buf_t, N);

    // 3. h1 = relu(agg1 @ W1 + b1)   [N,512]
    {
        dim3 grid((512 + GBN - 1) / GBN, (N + GBM - 1) / GBM);
        k_gemm<<<grid, 256, 0, stream>>>(buf_t, W1, b1, nullptr, h1, N, 512, 128, 1);
    }

    // 4. t = dinv[row] * (h1 @ W2)   [N,250]  (row-scale fused in epilogue)
    {
        dim3 grid((250 + GBN - 1) / GBN, (N + GBM - 1) / GBM);
        k_gemm<<<grid, 256, 0, stream>>>(h1, W2, nullptr, dinv, buf_t, N, 250, 512, 0);
    }

    // 5. layer 2 aggregation (pull) + bias + relu -> out  [N,250]
    k_pull250<<<N, 256, 0, stream>>>(rowptr, adj, dinv, buf_t, b2, out, N);
}

// Round 3
// 485.733 us; speedup vs baseline: 4.1015x; 2.2678x over previous
//
#include <hip/hip_runtime.h>

#define N_NODES 50000

typedef __attribute__((ext_vector_type(8))) short bf16x8;
typedef __attribute__((ext_vector_type(4))) float f32x4;

__device__ __forceinline__ ushort f2bf(float f) {
    union { float f; unsigned u; } v; v.f = f;
    unsigned r = v.u + 0x7fff + ((v.u >> 16) & 1);   // round-to-nearest-even
    return (ushort)(r >> 16);
}
__device__ __forceinline__ float bf2f(ushort u) {
    union { unsigned u; float f; } v; v.u = ((unsigned)u) << 16;
    return v.f;
}

// ---------------- index-width detection (int64 vs int32 edge_index) --------
__global__ void k_detect(const void* ei, int* flag) {
    __shared__ int bad;
    if (threadIdx.x == 0) bad = 0;
    __syncthreads();
    long long v = ((const long long*)ei)[threadIdx.x];
    if (v < 0 || v >= N_NODES) atomicOr(&bad, 1);
    __syncthreads();
    if (threadIdx.x == 0) *flag = bad ? 0 : 1;
}

__device__ __forceinline__ int eload(const void* ei, int idx, int is64) {
    return is64 ? (int)((const long long*)ei)[idx] : ((const int*)ei)[idx];
}

// ---------------- CSR build ----------------
__global__ void k_zero_int(int* p, int n) {
    int i = blockIdx.x * blockDim.x + threadIdx.x;
    if (i < n) p[i] = 0;
}

__global__ void k_hist(const void* ei, const int* flag, int* deg, int e) {
    int i = blockIdx.x * blockDim.x + threadIdx.x;
    if (i >= e) return;
    int is64 = *flag;
    int d = eload(ei, e + i, is64);
    atomicAdd(&deg[d], 1);
}

__global__ void k_dinv(const int* deg, float* dinv, int n) {
    int i = blockIdx.x * blockDim.x + threadIdx.x;
    if (i < n) dinv[i] = rsqrtf((float)(deg[i] + 1));  // +1 self-loop
}

// single-block chunked inclusive scan -> rowptr[0..n], 1024 threads
__global__ void k_scan(const int* deg, int* rowptr, int n) {
    __shared__ int wsum[16];
    __shared__ int carry;
    const int tid = threadIdx.x;
    const int lane = tid & 63, wid = tid >> 6;
    if (tid == 0) { carry = 0; rowptr[0] = 0; }
    __syncthreads();
    for (int base = 0; base < n; base += 1024) {
        int v = (base + tid < n) ? deg[base + tid] : 0;
        int x = v;
        #pragma unroll
        for (int off = 1; off < 64; off <<= 1) {
            int y = __shfl_up(x, off, 64);
            if (lane >= off) x += y;
        }
        if (lane == 63) wsum[wid] = x;
        __syncthreads();
        if (wid == 0) {
            int s = (lane < 16) ? wsum[lane] : 0;
            #pragma unroll
            for (int off = 1; off < 16; off <<= 1) {
                int y = __shfl_up(s, off, 64);
                if (lane >= off) s += y;
            }
            if (lane < 16) wsum[lane] = s;
        }
        __syncthreads();
        int offset = carry + (wid > 0 ? wsum[wid - 1] : 0);
        if (base + tid < n) rowptr[base + tid + 1] = offset + x;
        __syncthreads();
        if (tid == 0) carry += wsum[15];
        __syncthreads();
    }
}

__global__ void k_copy_int(const int* a, int* b, int n) {
    int i = blockIdx.x * blockDim.x + threadIdx.x;
    if (i < n) b[i] = a[i];
}

__global__ void k_fill(const void* ei, const int* flag, int* cur, int* adj, int e) {
    int i = blockIdx.x * blockDim.x + threadIdx.x;
    if (i >= e) return;
    int is64 = *flag;
    int s = eload(ei, i, is64);
    int d = eload(ei, e + i, is64);
    int pos = atomicAdd(&cur[d], 1);
    adj[pos] = s;
}

// ---------------- weight transpose + split: Bt[n][k] = split(W[k][n]) -----
__global__ void k_splitT(const float* __restrict__ W, ushort* __restrict__ ohi,
                         ushort* __restrict__ olo, int R /*K*/, int C /*true N*/,
                         int Nout /*padded N*/) {
    int idx = blockIdx.x * blockDim.x + threadIdx.x;
    if (idx >= Nout * R) return;
    int n = idx / R;
    int k = idx - n * R;
    float v = (n < C) ? W[(size_t)k * C + n] : 0.0f;
    ushort hi = f2bf(v);
    ohi[idx] = hi;
    olo[idx] = f2bf(v - bf2f(hi));
}

// ---------------- pull aggregation, layer 1 (F=128) -> split bf16 --------
__global__ __launch_bounds__(256)
void k_pull128s(const int* __restrict__ rowptr, const int* __restrict__ adj,
                const float* __restrict__ dinv, const float* __restrict__ x,
                ushort* __restrict__ ohi, ushort* __restrict__ olo, int n) {
    const int i = blockIdx.x * 2 + (threadIdx.x >> 7);
    if (i >= n) return;
    const int f = threadIdx.x & 127;
    const float di = dinv[i];
    float acc = di * x[(size_t)i * 128 + f];
    int j = rowptr[i];
    const int end = rowptr[i + 1];
    for (; j + 4 <= end; j += 4) {
        int s0 = adj[j], s1 = adj[j + 1], s2 = adj[j + 2], s3 = adj[j + 3];
        float w0 = dinv[s0], w1 = dinv[s1], w2 = dinv[s2], w3 = dinv[s3];
        acc += w0 * x[(size_t)s0 * 128 + f];
        acc += w1 * x[(size_t)s1 * 128 + f];
        acc += w2 * x[(size_t)s2 * 128 + f];
        acc += w3 * x[(size_t)s3 * 128 + f];
    }
    for (; j < end; ++j) {
        int s = adj[j];
        acc += dinv[s] * x[(size_t)s * 128 + f];
    }
    float v = di * acc;
    ushort hi = f2bf(v);
    ohi[(size_t)i * 128 + f] = hi;
    olo[(size_t)i * 128 + f] = f2bf(v - bf2f(hi));
}

// ---------------- pull aggregation, layer 2 (F=250, t bf16 ld=256) -------
__global__ __launch_bounds__(256)
void k_pull250b(const int* __restrict__ rowptr, const int* __restrict__ adj,
                const float* __restrict__ dinv, const ushort* __restrict__ t,
                const float* __restrict__ bias, float* __restrict__ out, int n) {
    const int i = blockIdx.x;
    const int f = threadIdx.x;
    if (i >= n || f >= 250) return;
    float acc = bf2f(t[(size_t)i * 256 + f]);
    int j = rowptr[i];
    const int end = rowptr[i + 1];
    for (; j + 4 <= end; j += 4) {
        int s0 = adj[j], s1 = adj[j + 1], s2 = adj[j + 2], s3 = adj[j + 3];
        acc += bf2f(t[(size_t)s0 * 256 + f]);
        acc += bf2f(t[(size_t)s1 * 256 + f]);
        acc += bf2f(t[(size_t)s2 * 256 + f]);
        acc += bf2f(t[(size_t)s3 * 256 + f]);
    }
    for (; j < end; ++j)
        acc += bf2f(t[(size_t)adj[j] * 256 + f]);
    float v = dinv[i] * acc + bias[f];
    out[(size_t)i * 250 + f] = fmaxf(v, 0.0f);
}

// ---------------- split-bf16 MFMA GEMM: C = A[MxK] @ Bt[N][K]^T ----------
// A given as (Ahi,Alo) [M][K] bf16; B as (Bhi,Blo) [N][K] bf16 (transposed).
// acc f32 via 3 MFMA products: ah*bh + al*bh + ah*bl.
// mode 0: out_hi[r*ldc+c] = bf16( acc * rscale[r] )
// mode 1: v = relu(acc + bias[c]); out_hi = bf16hi(v), out_lo = bf16lo(v)
// Tile 128x128, BK=32, 4 waves. LDS layout per array: [chunk=k/8][row][8 bf16]
// (chunk stride padded to 1032 ushorts to spread banks).
#define OFF_AH 0
#define OFF_AL 4128
#define OFF_BH 8256
#define OFF_BL 12384

__device__ __forceinline__ void gl16(const ushort* g, const ushort* l) {
    __builtin_amdgcn_global_load_lds((const __attribute__((address_space(1))) void*)g,
                                     (__attribute__((address_space(3))) void*)l,
                                     16, 0, 0);
}

__global__ __launch_bounds__(256, 2)
void k_mfma_split(const ushort* __restrict__ Ahi, const ushort* __restrict__ Alo,
                  const ushort* __restrict__ Bhi, const ushort* __restrict__ Blo,
                  const float* __restrict__ bias, const float* __restrict__ rscale,
                  ushort* __restrict__ out_hi, ushort* __restrict__ out_lo,
                  int M, int K, int ldc, int mode) {
    __shared__ __align__(16) ushort smem[16512];
    const int tid  = threadIdx.x;
    const int lane = tid & 63;
    const int w    = tid >> 6;
    const int g    = lane >> 4;   // k-chunk group 0..3
    const int lr   = lane & 15;
    const int wm   = w >> 1, wn = w & 1;
    const int brow = blockIdx.y * 128;
    const int bcol = blockIdx.x * 128;

    f32x4 acc[4][4] = {};

    for (int k0 = 0; k0 < K; k0 += 32) {
        // ---- stage 4 arrays x [128 rows x 32 k] into LDS (8 gload/wave) ----
        #pragma unroll
        for (int t2 = 0; t2 < 2; ++t2) {
            const int b  = w * 2 + t2;        // 0..7 slot-block
            const int c  = b >> 1;            // k-chunk 0..3 (uniform per instr)
            const int r0 = (b & 1) * 64;      // row base
            const int koff = k0 + c * 8;
            const int drow = r0 + lane;
            const int doff = c * 1032 + r0 * 8;   // wave-uniform LDS base (ushorts)
            gl16(Ahi + (size_t)(brow + drow) * K + koff, smem + OFF_AH + doff);
            gl16(Alo + (size_t)(brow + drow) * K + koff, smem + OFF_AL + doff);
            gl16(Bhi + (size_t)(bcol + drow) * K + koff, smem + OFF_BH + doff);
            gl16(Blo + (size_t)(bcol + drow) * K + koff, smem + OFF_BL + doff);
        }
        __syncthreads();

        // ---- fragments: A row = lane&15, k = 8*(lane>>4)+j ----
        bf16x8 ah[4], al[4], bh[4], bl[4];
        #pragma unroll
        for (int i = 0; i < 4; ++i) {
            const int ao = g * 1032 + (wm * 64 + i * 16 + lr) * 8;
            ah[i] = *(const bf16x8*)(smem + OFF_AH + ao);
            al[i] = *(const bf16x8*)(smem + OFF_AL + ao);
            const int bo = g * 1032 + (wn * 64 + i * 16 + lr) * 8;
            bh[i] = *(const bf16x8*)(smem + OFF_BH + bo);
            bl[i] = *(const bf16x8*)(smem + OFF_BL + bo);
        }
        #pragma unroll
        for (int mt = 0; mt < 4; ++mt)
            #pragma unroll
            for (int nt = 0; nt < 4; ++nt) {
                acc[mt][nt] = __builtin_amdgcn_mfma_f32_16x16x32_bf16(ah[mt], bh[nt], acc[mt][nt], 0, 0, 0);
                acc[mt][nt] = __builtin_amdgcn_mfma_f32_16x16x32_bf16(al[mt], bh[nt], acc[mt][nt], 0, 0, 0);
                acc[mt][nt] = __builtin_amdgcn_mfma_f32_16x16x32_bf16(ah[mt], bl[nt], acc[mt][nt], 0, 0, 0);
            }
        __syncthreads();
    }

    // ---- epilogue: C/D layout col=lane&15, row=(lane>>4)*4+reg ----
    #pragma unroll
    for (int mt = 0; mt < 4; ++mt)
        #pragma unroll
        for (int nt = 0; nt < 4; ++nt) {
            const int gr0 = brow + wm * 64 + mt * 16 + g * 4;
            const int gc  = bcol + wn * 64 + nt * 16 + lr;
            if (mode == 0) {
                #pragma unroll
                for (int r = 0; r < 4; ++r) {
                    const int gr = gr0 + r;
                    if (gr < M)
                        out_hi[(size_t)gr * ldc + gc] = f2bf(acc[mt][nt][r] * rscale[gr]);
                }
            } else {
                const float bv = bias[gc];
                #pragma unroll
                for (int r = 0; r < 4; ++r) {
                    const int gr = gr0 + r;
                    if (gr < M) {
                        float v = fmaxf(acc[mt][nt][r] + bv, 0.0f);
                        ushort hi = f2bf(v);
                        out_hi[(size_t)gr * ldc + gc] = hi;
                        out_lo[(size_t)gr * ldc + gc] = f2bf(v - bf2f(hi));
                    }
                }
            }
        }
}

extern "C" void kernel_launch(void* const* d_in, const int* in_sizes, int n_in,
                              void* d_out, int out_size, void* d_ws, size_t ws_size,
                              hipStream_t stream) {
    const float* x  = (const float*)d_in[0];
    const void*  ei = d_in[1];
    const float* W1 = (const float*)d_in[2];
    const float* b1 = (const float*)d_in[3];
    const float* W2 = (const float*)d_in[4];
    const float* b2 = (const float*)d_in[5];
    float* out = (float*)d_out;

    const int N = N_NODES;
    const int E = in_sizes[1] / 2;
    const int MPAD = 50048;          // 391 * 128

    // ---- workspace layout (peak ~133 MB) ----
    char* base = (char*)d_ws;
    int*   flag   = (int*)base;                        // 256 B slot
    int*   deg    = (int*)(base + 256);                // [51200]
    int*   rowptr = deg + 51200;
    int*   cur    = rowptr + 51200;
    float* dinv   = (float*)(cur + 51200);
    int*   adj    = (int*)(dinv + 51200);              // [E]
    char*  p      = (char*)(adj + ((E + 63) & ~63));
    ushort* A1hi  = (ushort*)p;  p += (size_t)MPAD * 128 * 2;
    ushort* A1lo  = (ushort*)p;  p += (size_t)MPAD * 128 * 2;
    ushort* tbuf  = A1hi;        // [N][256] bf16 aliases A1 (dead after GEMM1)
    ushort* h1hi  = (ushort*)p;  p += (size_t)MPAD * 512 * 2;
    ushort* h1lo  = (ushort*)p;  p += (size_t)MPAD * 512 * 2;
    ushort* Bt1hi = (ushort*)p;  p += 512 * 128 * 2;
    ushort* Bt1lo = (ushort*)p;  p += 512 * 128 * 2;
    ushort* Bt2hi = (ushort*)p;  p += 256 * 512 * 2;
    ushort* Bt2lo = (ushort*)p;  p += 256 * 512 * 2;

    // 1. CSR build + normalization
    k_detect<<<1, 1024, 0, stream>>>(ei, flag);
    k_zero_int<<<(N + 255) / 256, 256, 0, stream>>>(deg, N);
    k_hist<<<(E + 255) / 256, 256, 0, stream>>>(ei, flag, deg, E);
    k_dinv<<<(N + 255) / 256, 256, 0, stream>>>(deg, dinv, N);
    k_scan<<<1, 1024, 0, stream>>>(deg, rowptr, N);
    k_copy_int<<<(N + 255) / 256, 256, 0, stream>>>(rowptr, cur, N);
    k_fill<<<(E + 255) / 256, 256, 0, stream>>>(ei, flag, cur, adj, E);

    // 2. weight prep: transpose + split
    k_splitT<<<(512 * 128 + 255) / 256, 256, 0, stream>>>(W1, Bt1hi, Bt1lo, 128, 512, 512);
    k_splitT<<<(256 * 512 + 255) / 256, 256, 0, stream>>>(W2, Bt2hi, Bt2lo, 512, 250, 256);

    // 3. layer-1 aggregation -> A1 (split bf16)  [N,128]
    k_pull128s<<<(N + 1) / 2, 256, 0, stream>>>(rowptr, adj, dinv, x, A1hi, A1lo, N);

    // 4. h1 = relu(A1 @ W1 + b1) -> split bf16 [N,512]
    {
        dim3 grid(512 / 128, (N + 127) / 128);
        k_mfma_split<<<grid, 256, 0, stream>>>(A1hi, A1lo, Bt1hi, Bt1lo,
                                               b1, nullptr, h1hi, h1lo,
                                               N, 128, 512, 1);
    }

    // 5. t = bf16( dinv[row] * (h1 @ W2) )  [N,256]
    {
        dim3 grid(256 / 128, (N + 127) / 128);
        k_mfma_split<<<grid, 256, 0, stream>>>(h1hi, h1lo, Bt2hi, Bt2lo,
                                               nullptr, dinv, tbuf, nullptr,
                                               N, 512, 256, 0);
    }

    // 6. layer-2 aggregation + bias + relu -> out  [N,250]
    k_pull250b<<<N, 256, 0, stream>>>(rowptr, adj, dinv, tbuf, b2, out, N);
}

// Round 4
// 470.195 us; speedup vs baseline: 4.2370x; 1.0330x over previous
//
#include <hip/hip_runtime.h>

#define N_NODES 50000

typedef __attribute__((ext_vector_type(8))) short bf16x8;
typedef __attribute__((ext_vector_type(4))) float f32x4;

__device__ __forceinline__ ushort f2bf(float f) {
    union { float f; unsigned u; } v; v.f = f;
    unsigned r = v.u + 0x7fff + ((v.u >> 16) & 1);   // round-to-nearest-even
    return (ushort)(r >> 16);
}
__device__ __forceinline__ float bf2f(ushort u) {
    union { unsigned u; float f; } v; v.u = ((unsigned)u) << 16;
    return v.f;
}
__device__ __forceinline__ float bf2f_lo(unsigned u) {   // low 16 bits as bf16
    union { unsigned u; float f; } v; v.u = u << 16;
    return v.f;
}
__device__ __forceinline__ float bf2f_hi(unsigned u) {   // high 16 bits as bf16
    union { unsigned u; float f; } v; v.u = u & 0xffff0000u;
    return v.f;
}

// ---------------- index-width detection (int64 vs int32 edge_index) --------
__global__ void k_detect(const void* ei, int* flag) {
    __shared__ int bad;
    if (threadIdx.x == 0) bad = 0;
    __syncthreads();
    long long v = ((const long long*)ei)[threadIdx.x];
    if (v < 0 || v >= N_NODES) atomicOr(&bad, 1);
    __syncthreads();
    if (threadIdx.x == 0) *flag = bad ? 0 : 1;
}

__device__ __forceinline__ int eload(const void* ei, int idx, int is64) {
    return is64 ? (int)((const long long*)ei)[idx] : ((const int*)ei)[idx];
}

// ---------------- CSR build ----------------
__global__ void k_hist(const void* ei, const int* flag, int* deg, int e) {
    int i = blockIdx.x * blockDim.x + threadIdx.x;
    if (i >= e) return;
    int is64 = *flag;
    int d = eload(ei, e + i, is64);
    atomicAdd(&deg[d], 1);
}

// single-block chunked inclusive scan -> rowptr[0..n]; also cur (excl) + dinv
__global__ void k_scan(const int* deg, int* rowptr, int* cur, float* dinv, int n) {
    __shared__ int wsum[16];
    __shared__ int carry;
    const int tid = threadIdx.x;
    const int lane = tid & 63, wid = tid >> 6;
    if (tid == 0) { carry = 0; rowptr[0] = 0; }
    __syncthreads();
    for (int base = 0; base < n; base += 1024) {
        int v = (base + tid < n) ? deg[base + tid] : 0;
        int x = v;
        #pragma unroll
        for (int off = 1; off < 64; off <<= 1) {
            int y = __shfl_up(x, off, 64);
            if (lane >= off) x += y;
        }
        if (lane == 63) wsum[wid] = x;
        __syncthreads();
        if (wid == 0) {
            int s = (lane < 16) ? wsum[lane] : 0;
            #pragma unroll
            for (int off = 1; off < 16; off <<= 1) {
                int y = __shfl_up(s, off, 64);
                if (lane >= off) s += y;
            }
            if (lane < 16) wsum[lane] = s;
        }
        __syncthreads();
        int offset = carry + (wid > 0 ? wsum[wid - 1] : 0);
        if (base + tid < n) {
            rowptr[base + tid + 1] = offset + x;
            cur[base + tid] = offset + x - v;          // exclusive prefix
            dinv[base + tid] = rsqrtf((float)(v + 1)); // +1 self-loop
        }
        __syncthreads();
        if (tid == 0) carry += wsum[15];
        __syncthreads();
    }
}

__global__ void k_fill(const void* ei, const int* flag, int* cur, int* adj, int e) {
    int i = blockIdx.x * blockDim.x + threadIdx.x;
    if (i >= e) return;
    int is64 = *flag;
    int s = eload(ei, i, is64);
    int d = eload(ei, e + i, is64);
    int pos = atomicAdd(&cur[d], 1);
    adj[pos] = s;
}

// ---------------- weight transpose + split: Bt[n][k] = split(W[k][n]) -----
__global__ void k_splitT(const float* __restrict__ W, ushort* __restrict__ ohi,
                         ushort* __restrict__ olo, int R /*K*/, int C /*true N*/,
                         int Nout /*padded N*/) {
    int idx = blockIdx.x * blockDim.x + threadIdx.x;
    if (idx >= Nout * R) return;
    int n = idx / R;
    int k = idx - n * R;
    float v = (n < C) ? W[(size_t)k * C + n] : 0.0f;
    ushort hi = f2bf(v);
    ohi[idx] = hi;
    olo[idx] = f2bf(v - bf2f(hi));
}

// ---------------- pull aggregation, layer 1 (F=128) -> split bf16 --------
__global__ __launch_bounds__(256)
void k_pull128s(const int* __restrict__ rowptr, const int* __restrict__ adj,
                const float* __restrict__ dinv, const float* __restrict__ x,
                ushort* __restrict__ ohi, ushort* __restrict__ olo, int n) {
    const int i = blockIdx.x * 2 + (threadIdx.x >> 7);
    if (i >= n) return;
    const int f = threadIdx.x & 127;
    const float di = dinv[i];
    float acc = di * x[(size_t)i * 128 + f];
    int j = rowptr[i];
    const int end = rowptr[i + 1];
    for (; j + 4 <= end; j += 4) {
        int s0 = adj[j], s1 = adj[j + 1], s2 = adj[j + 2], s3 = adj[j + 3];
        float w0 = dinv[s0], w1 = dinv[s1], w2 = dinv[s2], w3 = dinv[s3];
        acc += w0 * x[(size_t)s0 * 128 + f];
        acc += w1 * x[(size_t)s1 * 128 + f];
        acc += w2 * x[(size_t)s2 * 128 + f];
        acc += w3 * x[(size_t)s3 * 128 + f];
    }
    for (; j < end; ++j) {
        int s = adj[j];
        acc += dinv[s] * x[(size_t)s * 128 + f];
    }
    float v = di * acc;
    ushort hi = f2bf(v);
    ohi[(size_t)i * 128 + f] = hi;
    olo[(size_t)i * 128 + f] = f2bf(v - bf2f(hi));
}

// ---------------- pull aggregation, layer 2 (F=250, t bf16 ld=256) -------
// 2 rows per block, u32 (bf16x2) gathers, float2 stores
__global__ __launch_bounds__(256)
void k_pull250c(const int* __restrict__ rowptr, const int* __restrict__ adj,
                const float* __restrict__ dinv, const ushort* __restrict__ t,
                const float* __restrict__ bias, float* __restrict__ out, int n) {
    const int i = blockIdx.x * 2 + (threadIdx.x >> 7);
    const int f2 = threadIdx.x & 127;
    if (i >= n || f2 >= 125) return;
    const unsigned* t32 = (const unsigned*)t;     // [row][128] u32
    unsigned u = t32[(size_t)i * 128 + f2];
    float a0 = bf2f_lo(u), a1 = bf2f_hi(u);
    int j = rowptr[i];
    const int end = rowptr[i + 1];
    for (; j + 4 <= end; j += 4) {
        int s0 = adj[j], s1 = adj[j + 1], s2 = adj[j + 2], s3 = adj[j + 3];
        unsigned u0 = t32[(size_t)s0 * 128 + f2];
        unsigned u1 = t32[(size_t)s1 * 128 + f2];
        unsigned u2 = t32[(size_t)s2 * 128 + f2];
        unsigned u3 = t32[(size_t)s3 * 128 + f2];
        a0 += bf2f_lo(u0) + bf2f_lo(u1) + bf2f_lo(u2) + bf2f_lo(u3);
        a1 += bf2f_hi(u0) + bf2f_hi(u1) + bf2f_hi(u2) + bf2f_hi(u3);
    }
    for (; j < end; ++j) {
        unsigned us = t32[(size_t)adj[j] * 128 + f2];
        a0 += bf2f_lo(us);
        a1 += bf2f_hi(us);
    }
    const float d = dinv[i];
    float2 bv = *(const float2*)&bias[2 * f2];
    float2 o;
    o.x = fmaxf(d * a0 + bv.x, 0.0f);
    o.y = fmaxf(d * a1 + bv.y, 0.0f);
    *(float2*)&out[(size_t)i * 250 + 2 * f2] = o;
}

// ---------------- split-bf16 MFMA GEMM: C = A[MxK] @ Bt[N][K]^T ----------
// Operands SWAPPED in the mfma (compute D^T): lane holds 4 consecutive
// output COLS (reg r) at output row = lane&15 -> vectorized uint2 stores.
// mode 0: out_hi[r*ldc+c..c+3] = bf16( acc * rscale[r] )      (t, single bf16)
// mode 1: v = relu(acc + bias[c]); planar hi/lo bf16 outputs  (h1, split)
#define OFF_AH 0
#define OFF_AL 4128
#define OFF_BH 8256
#define OFF_BL 12384

__device__ __forceinline__ void gl16(const ushort* g, const ushort* l) {
    __builtin_amdgcn_global_load_lds((const __attribute__((address_space(1))) void*)g,
                                     (__attribute__((address_space(3))) void*)l,
                                     16, 0, 0);
}

__global__ __launch_bounds__(256, 3)
void k_mfma_split(const ushort* __restrict__ Ahi, const ushort* __restrict__ Alo,
                  const ushort* __restrict__ Bhi, const ushort* __restrict__ Blo,
                  const float* __restrict__ bias, const float* __restrict__ rscale,
                  ushort* __restrict__ out_hi, ushort* __restrict__ out_lo,
                  int M, int K, int ldc, int mode) {
    __shared__ __align__(16) ushort smem[16512];
    const int tid  = threadIdx.x;
    const int lane = tid & 63;
    const int w    = tid >> 6;
    const int g    = lane >> 4;   // k-chunk group 0..3
    const int lr   = lane & 15;
    const int wm   = w >> 1, wn = w & 1;
    const int brow = blockIdx.y * 128;
    const int bcol = blockIdx.x * 128;

    f32x4 acc[4][4] = {};

    for (int k0 = 0; k0 < K; k0 += 32) {
        // ---- stage 4 arrays x [128 rows x 32 k] into LDS (8 gload/wave) ----
        #pragma unroll
        for (int t2 = 0; t2 < 2; ++t2) {
            const int b  = w * 2 + t2;        // 0..7 slot-block
            const int c  = b >> 1;            // k-chunk 0..3 (uniform per instr)
            const int r0 = (b & 1) * 64;      // row base
            const int koff = k0 + c * 8;
            const int drow = r0 + lane;
            const int doff = c * 1032 + r0 * 8;   // wave-uniform LDS base (ushorts)
            gl16(Ahi + (size_t)(brow + drow) * K + koff, smem + OFF_AH + doff);
            gl16(Alo + (size_t)(brow + drow) * K + koff, smem + OFF_AL + doff);
            gl16(Bhi + (size_t)(bcol + drow) * K + koff, smem + OFF_BH + doff);
            gl16(Blo + (size_t)(bcol + drow) * K + koff, smem + OFF_BL + doff);
        }
        __syncthreads();

        // ---- fragments: row = lane&15, k = 8*(lane>>4)+j ----
        bf16x8 ah[4], al[4], bh[4], bl[4];
        #pragma unroll
        for (int i = 0; i < 4; ++i) {
            const int ao = g * 1032 + (wm * 64 + i * 16 + lr) * 8;
            ah[i] = *(const bf16x8*)(smem + OFF_AH + ao);
            al[i] = *(const bf16x8*)(smem + OFF_AL + ao);
            const int bo = g * 1032 + (wn * 64 + i * 16 + lr) * 8;
            bh[i] = *(const bf16x8*)(smem + OFF_BH + bo);
            bl[i] = *(const bf16x8*)(smem + OFF_BL + bo);
        }
        // SWAPPED operands: D^T tile; reg r = output col, lane&15 = output row
        #pragma unroll
        for (int mt = 0; mt < 4; ++mt)
            #pragma unroll
            for (int nt = 0; nt < 4; ++nt) {
                acc[mt][nt] = __builtin_amdgcn_mfma_f32_16x16x32_bf16(bh[nt], ah[mt], acc[mt][nt], 0, 0, 0);
                acc[mt][nt] = __builtin_amdgcn_mfma_f32_16x16x32_bf16(bh[nt], al[mt], acc[mt][nt], 0, 0, 0);
                acc[mt][nt] = __builtin_amdgcn_mfma_f32_16x16x32_bf16(bl[nt], ah[mt], acc[mt][nt], 0, 0, 0);
            }
        __syncthreads();
    }

    // ---- epilogue: row = brow+wm*64+mt*16+lr, cols = bcol+wn*64+nt*16+g*4+r
    #pragma unroll
    for (int mt = 0; mt < 4; ++mt) {
        const int gr = brow + wm * 64 + mt * 16 + lr;
        if (gr >= M) continue;
        #pragma unroll
        for (int nt = 0; nt < 4; ++nt) {
            const int gc0 = bcol + wn * 64 + nt * 16 + g * 4;
            if (mode == 0) {
                const float rs = rscale[gr];
                unsigned h0 = f2bf(acc[mt][nt][0] * rs) | ((unsigned)f2bf(acc[mt][nt][1] * rs) << 16);
                unsigned h1 = f2bf(acc[mt][nt][2] * rs) | ((unsigned)f2bf(acc[mt][nt][3] * rs) << 16);
                uint2 pk; pk.x = h0; pk.y = h1;
                *(uint2*)(out_hi + (size_t)gr * ldc + gc0) = pk;
            } else {
                const float4 bv = *(const float4*)&bias[gc0];
                float v0 = fmaxf(acc[mt][nt][0] + bv.x, 0.0f);
                float v1 = fmaxf(acc[mt][nt][1] + bv.y, 0.0f);
                float v2 = fmaxf(acc[mt][nt][2] + bv.z, 0.0f);
                float v3 = fmaxf(acc[mt][nt][3] + bv.w, 0.0f);
                ushort h0 = f2bf(v0), h1 = f2bf(v1), h2 = f2bf(v2), h3 = f2bf(v3);
                uint2 hp; hp.x = (unsigned)h0 | ((unsigned)h1 << 16);
                hp.y = (unsigned)h2 | ((unsigned)h3 << 16);
                *(uint2*)(out_hi + (size_t)gr * ldc + gc0) = hp;
                ushort l0 = f2bf(v0 - bf2f(h0)), l1 = f2bf(v1 - bf2f(h1));
                ushort l2 = f2bf(v2 - bf2f(h2)), l3 = f2bf(v3 - bf2f(h3));
                uint2 lp; lp.x = (unsigned)l0 | ((unsigned)l1 << 16);
                lp.y = (unsigned)l2 | ((unsigned)l3 << 16);
                *(uint2*)(out_lo + (size_t)gr * ldc + gc0) = lp;
            }
        }
    }
}

extern "C" void kernel_launch(void* const* d_in, const int* in_sizes, int n_in,
                              void* d_out, int out_size, void* d_ws, size_t ws_size,
                              hipStream_t stream) {
    const float* x  = (const float*)d_in[0];
    const void*  ei = d_in[1];
    const float* W1 = (const float*)d_in[2];
    const float* b1 = (const float*)d_in[3];
    const float* W2 = (const float*)d_in[4];
    const float* b2 = (const float*)d_in[5];
    float* out = (float*)d_out;

    const int N = N_NODES;
    const int E = in_sizes[1] / 2;
    const int MPAD = 50048;          // 391 * 128

    // ---- workspace layout (peak ~133 MB) ----
    char* base = (char*)d_ws;
    int*   flag   = (int*)base;                        // 256 B slot
    int*   deg    = (int*)(base + 256);                // [51200]
    int*   rowptr = deg + 51200;
    int*   cur    = rowptr + 51200;
    float* dinv   = (float*)(cur + 51200);
    int*   adj    = (int*)(dinv + 51200);              // [E]
    char*  p      = (char*)(adj + ((E + 63) & ~63));
    ushort* A1hi  = (ushort*)p;  p += (size_t)MPAD * 128 * 2;
    ushort* A1lo  = (ushort*)p;  p += (size_t)MPAD * 128 * 2;
    ushort* tbuf  = A1hi;        // [N][256] bf16 aliases A1 (dead after GEMM1)
    ushort* h1hi  = (ushort*)p;  p += (size_t)MPAD * 512 * 2;
    ushort* h1lo  = (ushort*)p;  p += (size_t)MPAD * 512 * 2;
    ushort* Bt1hi = (ushort*)p;  p += 512 * 128 * 2;
    ushort* Bt1lo = (ushort*)p;  p += 512 * 128 * 2;
    ushort* Bt2hi = (ushort*)p;  p += 256 * 512 * 2;
    ushort* Bt2lo = (ushort*)p;  p += 256 * 512 * 2;

    // 1. CSR build + normalization
    k_detect<<<1, 1024, 0, stream>>>(ei, flag);
    hipMemsetAsync(deg, 0, (size_t)N * sizeof(int), stream);
    k_hist<<<(E + 255) / 256, 256, 0, stream>>>(ei, flag, deg, E);
    k_scan<<<1, 1024, 0, stream>>>(deg, rowptr, cur, dinv, N);
    k_fill<<<(E + 255) / 256, 256, 0, stream>>>(ei, flag, cur, adj, E);

    // 2. weight prep: transpose + split
    k_splitT<<<(512 * 128 + 255) / 256, 256, 0, stream>>>(W1, Bt1hi, Bt1lo, 128, 512, 512);
    k_splitT<<<(256 * 512 + 255) / 256, 256, 0, stream>>>(W2, Bt2hi, Bt2lo, 512, 250, 256);

    // 3. layer-1 aggregation -> A1 (split bf16)  [N,128]
    k_pull128s<<<(N + 1) / 2, 256, 0, stream>>>(rowptr, adj, dinv, x, A1hi, A1lo, N);

    // 4. h1 = relu(A1 @ W1 + b1) -> split bf16 [N,512]
    {
        dim3 grid(512 / 128, (N + 127) / 128);
        k_mfma_split<<<grid, 256, 0, stream>>>(A1hi, A1lo, Bt1hi, Bt1lo,
                                               b1, nullptr, h1hi, h1lo,
                                               N, 128, 512, 1);
    }

    // 5. t = bf16( dinv[row] * (h1 @ W2) )  [N,256]
    {
        dim3 grid(256 / 128, (N + 127) / 128);
        k_mfma_split<<<grid, 256, 0, stream>>>(h1hi, h1lo, Bt2hi, Bt2lo,
                                               nullptr, dinv, tbuf, nullptr,
                                               N, 512, 256, 0);
    }

    // 6. layer-2 aggregation + bias + relu -> out  [N,250]
    k_pull250c<<<(N + 1) / 2, 256, 0, stream>>>(rowptr, adj, dinv, tbuf, b2, out, N);
}

// Round 5
// 413.946 us; speedup vs baseline: 4.8127x; 1.1359x over previous
//
#include <hip/hip_runtime.h>

#define N_NODES 50000

typedef __attribute__((ext_vector_type(8))) short bf16x8;
typedef __attribute__((ext_vector_type(4))) float f32x4;

__device__ __forceinline__ ushort f2bf(float f) {
    union { float f; unsigned u; } v; v.f = f;
    unsigned r = v.u + 0x7fff + ((v.u >> 16) & 1);   // round-to-nearest-even
    return (ushort)(r >> 16);
}
__device__ __forceinline__ float bf2f(ushort u) {
    union { unsigned u; float f; } v; v.u = ((unsigned)u) << 16;
    return v.f;
}
__device__ __forceinline__ float bf2f_lo(unsigned u) {
    union { unsigned u; float f; } v; v.u = u << 16;
    return v.f;
}
__device__ __forceinline__ float bf2f_hi(unsigned u) {
    union { unsigned u; float f; } v; v.u = u & 0xffff0000u;
    return v.f;
}

// ---------------- index-width detection (int64 vs int32 edge_index) --------
__global__ void k_detect(const void* ei, int* flag) {
    __shared__ int bad;
    if (threadIdx.x == 0) bad = 0;
    __syncthreads();
    long long v = ((const long long*)ei)[threadIdx.x];
    if (v < 0 || v >= N_NODES) atomicOr(&bad, 1);
    __syncthreads();
    if (threadIdx.x == 0) *flag = bad ? 0 : 1;
}

__device__ __forceinline__ int eload(const void* ei, int idx, int is64) {
    return is64 ? (int)((const long long*)ei)[idx] : ((const int*)ei)[idx];
}

// ---------------- CSR build ----------------
__global__ void k_hist(const void* ei, const int* flag, int* deg, int e) {
    int i = blockIdx.x * blockDim.x + threadIdx.x;
    if (i >= e) return;
    int is64 = *flag;
    int d = eload(ei, e + i, is64);
    atomicAdd(&deg[d], 1);
}

// single-block chunked inclusive scan -> rowptr[0..n]; also cur (excl) + dinv
__global__ void k_scan(const int* deg, int* rowptr, int* cur, float* dinv, int n) {
    __shared__ int wsum[16];
    __shared__ int carry;
    const int tid = threadIdx.x;
    const int lane = tid & 63, wid = tid >> 6;
    if (tid == 0) { carry = 0; rowptr[0] = 0; }
    __syncthreads();
    for (int base = 0; base < n; base += 1024) {
        int v = (base + tid < n) ? deg[base + tid] : 0;
        int x = v;
        #pragma unroll
        for (int off = 1; off < 64; off <<= 1) {
            int y = __shfl_up(x, off, 64);
            if (lane >= off) x += y;
        }
        if (lane == 63) wsum[wid] = x;
        __syncthreads();
        if (wid == 0) {
            int s = (lane < 16) ? wsum[lane] : 0;
            #pragma unroll
            for (int off = 1; off < 16; off <<= 1) {
                int y = __shfl_up(s, off, 64);
                if (lane >= off) s += y;
            }
            if (lane < 16) wsum[lane] = s;
        }
        __syncthreads();
        int offset = carry + (wid > 0 ? wsum[wid - 1] : 0);
        if (base + tid < n) {
            rowptr[base + tid + 1] = offset + x;
            cur[base + tid] = offset + x - v;          // exclusive prefix
            dinv[base + tid] = rsqrtf((float)(v + 1)); // +1 self-loop
        }
        __syncthreads();
        if (tid == 0) carry += wsum[15];
        __syncthreads();
    }
}

__global__ void k_fill(const void* ei, const int* flag, int* cur, int* adj, int e) {
    int i = blockIdx.x * blockDim.x + threadIdx.x;
    if (i >= e) return;
    int is64 = *flag;
    int s = eload(ei, i, is64);
    int d = eload(ei, e + i, is64);
    int pos = atomicAdd(&cur[d], 1);
    adj[pos] = s;
}

// ---------------- weight transpose + split: Bt[n][k] = split(W[k][n]) -----
__global__ void k_splitT(const float* __restrict__ W, ushort* __restrict__ ohi,
                         ushort* __restrict__ olo, int R /*K*/, int C /*true N*/,
                         int Nout /*padded N*/) {
    int idx = blockIdx.x * blockDim.x + threadIdx.x;
    if (idx >= Nout * R) return;
    int n = idx / R;
    int k = idx - n * R;
    float v = (n < C) ? W[(size_t)k * C + n] : 0.0f;
    ushort hi = f2bf(v);
    ohi[idx] = hi;
    olo[idx] = f2bf(v - bf2f(hi));
}

// ---------------- pull aggregation, layer 1 (F=128) -> split bf16 --------
__global__ __launch_bounds__(256)
void k_pull128s(const int* __restrict__ rowptr, const int* __restrict__ adj,
                const float* __restrict__ dinv, const float* __restrict__ x,
                ushort* __restrict__ ohi, ushort* __restrict__ olo, int n) {
    const int i = blockIdx.x * 2 + (threadIdx.x >> 7);
    if (i >= n) return;
    const int f = threadIdx.x & 127;
    const float di = dinv[i];
    float acc = di * x[(size_t)i * 128 + f];
    int j = rowptr[i];
    const int end = rowptr[i + 1];
    for (; j + 4 <= end; j += 4) {
        int s0 = adj[j], s1 = adj[j + 1], s2 = adj[j + 2], s3 = adj[j + 3];
        float w0 = dinv[s0], w1 = dinv[s1], w2 = dinv[s2], w3 = dinv[s3];
        acc += w0 * x[(size_t)s0 * 128 + f];
        acc += w1 * x[(size_t)s1 * 128 + f];
        acc += w2 * x[(size_t)s2 * 128 + f];
        acc += w3 * x[(size_t)s3 * 128 + f];
    }
    for (; j < end; ++j) {
        int s = adj[j];
        acc += dinv[s] * x[(size_t)s * 128 + f];
    }
    float v = di * acc;
    ushort hi = f2bf(v);
    ohi[(size_t)i * 128 + f] = hi;
    olo[(size_t)i * 128 + f] = f2bf(v - bf2f(hi));
}

// ---------------- pull aggregation, layer 2 (F=250, t bf16 ld=256) -------
__global__ __launch_bounds__(256)
void k_pull250c(const int* __restrict__ rowptr, const int* __restrict__ adj,
                const float* __restrict__ dinv, const ushort* __restrict__ t,
                const float* __restrict__ bias, float* __restrict__ out, int n) {
    const int i = blockIdx.x * 2 + (threadIdx.x >> 7);
    const int f2 = threadIdx.x & 127;
    if (i >= n || f2 >= 125) return;
    const unsigned* t32 = (const unsigned*)t;     // [row][128] u32
    unsigned u = t32[(size_t)i * 128 + f2];
    float a0 = bf2f_lo(u), a1 = bf2f_hi(u);
    int j = rowptr[i];
    const int end = rowptr[i + 1];
    for (; j + 4 <= end; j += 4) {
        int s0 = adj[j], s1 = adj[j + 1], s2 = adj[j + 2], s3 = adj[j + 3];
        unsigned u0 = t32[(size_t)s0 * 128 + f2];
        unsigned u1 = t32[(size_t)s1 * 128 + f2];
        unsigned u2 = t32[(size_t)s2 * 128 + f2];
        unsigned u3 = t32[(size_t)s3 * 128 + f2];
        a0 += bf2f_lo(u0) + bf2f_lo(u1) + bf2f_lo(u2) + bf2f_lo(u3);
        a1 += bf2f_hi(u0) + bf2f_hi(u1) + bf2f_hi(u2) + bf2f_hi(u3);
    }
    for (; j < end; ++j) {
        unsigned us = t32[(size_t)adj[j] * 128 + f2];
        a0 += bf2f_lo(us);
        a1 += bf2f_hi(us);
    }
    const float d = dinv[i];
    float2 bv = *(const float2*)&bias[2 * f2];
    float2 o;
    o.x = fmaxf(d * a0 + bv.x, 0.0f);
    o.y = fmaxf(d * a1 + bv.y, 0.0f);
    *(float2*)&out[(size_t)i * 250 + 2 * f2] = o;
}

// ---------------- split-bf16 MFMA GEMM, dbuf 2-phase, XCD swizzle --------
// NA = # A planes (2: hi+lo, 3 products; 1: hi only, 2 products).
// B always split (2 planes). Swapped mfma operands -> lane holds 4
// consecutive output cols. Output: single bf16 plane.
// mode 0: out = bf16(acc * rscale[row]); mode 1: out = bf16(relu(acc+bias[col]))
__device__ __forceinline__ void gl16(const ushort* g, ushort* l) {
    __builtin_amdgcn_global_load_lds((const __attribute__((address_space(1))) void*)g,
                                     (__attribute__((address_space(3))) void*)l,
                                     16, 0, 0);
}

template<int NA>
__global__ __launch_bounds__(256, NA == 1 ? 3 : 2)
void k_mfma(const ushort* __restrict__ Ahi, const ushort* __restrict__ Alo,
            const ushort* __restrict__ Bhi, const ushort* __restrict__ Blo,
            const float* __restrict__ bias, const float* __restrict__ rscale,
            ushort* __restrict__ outp, int M, int K, int ldc, int mode,
            int CX, int PY) {
    constexpr int NARR = NA + 2;
    __shared__ __align__(16) ushort smem[2 * NARR * 4128];

    // ---- XCD swizzle decode: a panel's CX col-blocks get ids ≡ same (mod 8)
    int id = blockIdx.x;
    const int gsz = CX * 8;
    const int nfull = (PY >> 3) * gsz;
    int bx, by;
    if (id < nfull) {
        int gg = id / gsz;
        int r  = id - gg * gsz;
        bx = r >> 3;
        by = gg * 8 + (r & 7);
    } else {
        int rem  = id - nfull;
        int pbase = (PY >> 3) << 3;
        int prem  = PY - pbase;
        by = pbase + rem % prem;
        bx = rem / prem;
    }
    const int brow = by * 128;
    const int bcol = bx * 128;

    const int tid  = threadIdx.x;
    const int lane = tid & 63;
    const int w    = tid >> 6;
    const int g    = lane >> 4;
    const int lr   = lane & 15;
    const int wm   = w >> 1, wn = w & 1;

    const ushort* srcs[NARR];
    if constexpr (NA == 2) { srcs[0] = Ahi; srcs[1] = Alo; srcs[2] = Bhi; srcs[3] = Blo; }
    else                   { srcs[0] = Ahi; srcs[1] = Bhi; srcs[2] = Blo; }

    auto STAGE = [&](ushort* buf, int k0) {
        #pragma unroll
        for (int a = 0; a < NARR; ++a) {
            const int rbase = (a < NA) ? brow : bcol;
            #pragma unroll
            for (int t2 = 0; t2 < 2; ++t2) {
                const int b  = w * 2 + t2;
                const int c  = b >> 1;
                const int r0 = (b & 1) * 64;
                gl16(srcs[a] + (size_t)(rbase + r0 + lane) * K + k0 + c * 8,
                     buf + a * 4128 + c * 1032 + r0 * 8);
            }
        }
    };

    f32x4 acc[4][4] = {};

    STAGE(smem, 0);
    __syncthreads();
    int cur = 0;

    for (int k0 = 0; k0 < K; k0 += 32) {
        ushort* rb = smem + cur * (NARR * 4128);
        if (k0 + 32 < K)
            STAGE(smem + (cur ^ 1) * (NARR * 4128), k0 + 32);

        bf16x8 af[NA][4], bhf[4], blf[4];
        #pragma unroll
        for (int i = 0; i < 4; ++i) {
            const int ao = g * 1032 + (wm * 64 + i * 16 + lr) * 8;
            #pragma unroll
            for (int a = 0; a < NA; ++a)
                af[a][i] = *(const bf16x8*)(rb + a * 4128 + ao);
            const int bo = g * 1032 + (wn * 64 + i * 16 + lr) * 8;
            bhf[i] = *(const bf16x8*)(rb + NA * 4128 + bo);
            blf[i] = *(const bf16x8*)(rb + (NA + 1) * 4128 + bo);
        }
        #pragma unroll
        for (int mt = 0; mt < 4; ++mt)
            #pragma unroll
            for (int nt = 0; nt < 4; ++nt) {
                acc[mt][nt] = __builtin_amdgcn_mfma_f32_16x16x32_bf16(bhf[nt], af[0][mt], acc[mt][nt], 0, 0, 0);
                if constexpr (NA == 2)
                    acc[mt][nt] = __builtin_amdgcn_mfma_f32_16x16x32_bf16(bhf[nt], af[1][mt], acc[mt][nt], 0, 0, 0);
                acc[mt][nt] = __builtin_amdgcn_mfma_f32_16x16x32_bf16(blf[nt], af[0][mt], acc[mt][nt], 0, 0, 0);
            }
        __syncthreads();
        cur ^= 1;
    }

    // ---- epilogue: row = brow+wm*64+mt*16+lr, cols = bcol+wn*64+nt*16+g*4+r
    #pragma unroll
    for (int mt = 0; mt < 4; ++mt) {
        const int gr = brow + wm * 64 + mt * 16 + lr;
        if (gr >= M) continue;
        const float rs = (mode == 0) ? rscale[gr] : 0.0f;
        #pragma unroll
        for (int nt = 0; nt < 4; ++nt) {
            const int gc0 = bcol + wn * 64 + nt * 16 + g * 4;
            float v0, v1, v2, v3;
            if (mode == 0) {
                v0 = acc[mt][nt][0] * rs; v1 = acc[mt][nt][1] * rs;
                v2 = acc[mt][nt][2] * rs; v3 = acc[mt][nt][3] * rs;
            } else {
                const float4 bv = *(const float4*)&bias[gc0];
                v0 = fmaxf(acc[mt][nt][0] + bv.x, 0.0f);
                v1 = fmaxf(acc[mt][nt][1] + bv.y, 0.0f);
                v2 = fmaxf(acc[mt][nt][2] + bv.z, 0.0f);
                v3 = fmaxf(acc[mt][nt][3] + bv.w, 0.0f);
            }
            uint2 pk;
            pk.x = (unsigned)f2bf(v0) | ((unsigned)f2bf(v1) << 16);
            pk.y = (unsigned)f2bf(v2) | ((unsigned)f2bf(v3) << 16);
            *(uint2*)(outp + (size_t)gr * ldc + gc0) = pk;
        }
    }
}

extern "C" void kernel_launch(void* const* d_in, const int* in_sizes, int n_in,
                              void* d_out, int out_size, void* d_ws, size_t ws_size,
                              hipStream_t stream) {
    const float* x  = (const float*)d_in[0];
    const void*  ei = d_in[1];
    const float* W1 = (const float*)d_in[2];
    const float* b1 = (const float*)d_in[3];
    const float* W2 = (const float*)d_in[4];
    const float* b2 = (const float*)d_in[5];
    float* out = (float*)d_out;

    const int N = N_NODES;
    const int E = in_sizes[1] / 2;
    const int MPAD = 50048;          // 391 * 128

    // ---- workspace layout ----
    char* base = (char*)d_ws;
    int*   flag   = (int*)base;                        // 256 B slot
    int*   deg    = (int*)(base + 256);                // [51200]
    int*   rowptr = deg + 51200;
    int*   cur    = rowptr + 51200;
    float* dinv   = (float*)(cur + 51200);
    int*   adj    = (int*)(dinv + 51200);              // [E]
    char*  p      = (char*)(adj + ((E + 63) & ~63));
    ushort* A1hi  = (ushort*)p;  p += (size_t)MPAD * 128 * 2;
    ushort* A1lo  = (ushort*)p;  p += (size_t)MPAD * 128 * 2;
    ushort* tbuf  = A1hi;        // [N][256] bf16 aliases A1 (dead after GEMM1)
    ushort* h1hi  = (ushort*)p;  p += (size_t)MPAD * 512 * 2;   // plain bf16
    ushort* Bt1hi = (ushort*)p;  p += 512 * 128 * 2;
    ushort* Bt1lo = (ushort*)p;  p += 512 * 128 * 2;
    ushort* Bt2hi = (ushort*)p;  p += 256 * 512 * 2;
    ushort* Bt2lo = (ushort*)p;  p += 256 * 512 * 2;

    // 1. CSR build + normalization
    k_detect<<<1, 1024, 0, stream>>>(ei, flag);
    hipMemsetAsync(deg, 0, (size_t)N * sizeof(int), stream);
    k_hist<<<(E + 255) / 256, 256, 0, stream>>>(ei, flag, deg, E);
    k_scan<<<1, 1024, 0, stream>>>(deg, rowptr, cur, dinv, N);
    k_fill<<<(E + 255) / 256, 256, 0, stream>>>(ei, flag, cur, adj, E);

    // 2. weight prep: transpose + split
    k_splitT<<<(512 * 128 + 255) / 256, 256, 0, stream>>>(W1, Bt1hi, Bt1lo, 128, 512, 512);
    k_splitT<<<(256 * 512 + 255) / 256, 256, 0, stream>>>(W2, Bt2hi, Bt2lo, 512, 250, 256);

    // 3. layer-1 aggregation -> A1 (split bf16)  [N,128]
    k_pull128s<<<(N + 1) / 2, 256, 0, stream>>>(rowptr, adj, dinv, x, A1hi, A1lo, N);

    // 4. h1 = relu(A1 @ W1 + b1) -> plain bf16 [N,512]   (NA=2, 3 products)
    k_mfma<2><<<4 * 391, 256, 0, stream>>>(A1hi, A1lo, Bt1hi, Bt1lo,
                                           b1, nullptr, h1hi,
                                           N, 128, 512, 1, 4, 391);

    // 5. t = bf16( dinv[row] * (h1 @ W2) )  [N,256]      (NA=1, 2 products)
    k_mfma<1><<<2 * 391, 256, 0, stream>>>(h1hi, nullptr, Bt2hi, Bt2lo,
                                           nullptr, dinv, tbuf,
                                           N, 512, 256, 0, 2, 391);

    // 6. layer-2 aggregation + bias + relu -> out  [N,250]
    k_pull250c<<<(N + 1) / 2, 256, 0, stream>>>(rowptr, adj, dinv, tbuf, b2, out, N);
}

// Round 6
// 347.112 us; speedup vs baseline: 5.7394x; 1.1925x over previous
//
#include <hip/hip_runtime.h>

#define N_NODES 50000

typedef __attribute__((ext_vector_type(8))) short bf16x8;
typedef __attribute__((ext_vector_type(4))) float f32x4;

__device__ __forceinline__ ushort f2bf(float f) {
    union { float f; unsigned u; } v; v.f = f;
    unsigned r = v.u + 0x7fff + ((v.u >> 16) & 1);   // round-to-nearest-even
    return (ushort)(r >> 16);
}
__device__ __forceinline__ float bf2f(ushort u) {
    union { unsigned u; float f; } v; v.u = ((unsigned)u) << 16;
    return v.f;
}
__device__ __forceinline__ float bf2f_lo(unsigned u) {
    union { unsigned u; float f; } v; v.u = u << 16;
    return v.f;
}
__device__ __forceinline__ float bf2f_hi(unsigned u) {
    union { unsigned u; float f; } v; v.u = u & 0xffff0000u;
    return v.f;
}

// ---------------- index-width detection (int64 vs int32 edge_index) --------
__global__ void k_detect(const void* ei, int* flag) {
    __shared__ int bad;
    if (threadIdx.x == 0) bad = 0;
    __syncthreads();
    long long v = ((const long long*)ei)[threadIdx.x];
    if (v < 0 || v >= N_NODES) atomicOr(&bad, 1);
    __syncthreads();
    if (threadIdx.x == 0) *flag = bad ? 0 : 1;
}

__device__ __forceinline__ int eload(const void* ei, int idx, int is64) {
    return is64 ? (int)((const long long*)ei)[idx] : ((const int*)ei)[idx];
}

// ---------------- CSR build ----------------
__global__ void k_hist(const void* ei, const int* flag, int* deg, int e) {
    int i = blockIdx.x * blockDim.x + threadIdx.x;
    if (i >= e) return;
    int is64 = *flag;
    int d = eload(ei, e + i, is64);
    atomicAdd(&deg[d], 1);
}

// ---- device-wide scan, 3 kernels ----
// A: per-block (512) inclusive scan of deg -> rp1 (local), block total -> bsum
__global__ __launch_bounds__(512)
void k_scanA(const int* __restrict__ deg, int* __restrict__ rp1,
             int* __restrict__ bsum, int n) {
    __shared__ int wsum[8];
    const int i = blockIdx.x * 512 + threadIdx.x;
    const int lane = threadIdx.x & 63, wid = threadIdx.x >> 6;
    int x = (i < n) ? deg[i] : 0;
    #pragma unroll
    for (int off = 1; off < 64; off <<= 1) {
        int y = __shfl_up(x, off, 64);
        if (lane >= off) x += y;
    }
    if (lane == 63) wsum[wid] = x;
    __syncthreads();
    if (wid == 0 && lane < 8) {
        int s = wsum[lane];
        #pragma unroll
        for (int off = 1; off < 8; off <<= 1) {
            int y = __shfl_up(s, off, 64);
            if (lane >= off) s += y;
        }
        wsum[lane] = s;
    }
    __syncthreads();
    int incl = x + (wid > 0 ? wsum[wid - 1] : 0);
    if (i < n) rp1[i] = incl;
    if (threadIdx.x == 0) bsum[blockIdx.x] = wsum[7];
}

// B: single block, inclusive scan of nb (<=128) block sums in-place
__global__ void k_scanB(int* bsum, int nb) {
    __shared__ int ws2[2];
    const int lane = threadIdx.x & 63, wid = threadIdx.x >> 6;
    int x = (threadIdx.x < nb) ? bsum[threadIdx.x] : 0;
    #pragma unroll
    for (int off = 1; off < 64; off <<= 1) {
        int y = __shfl_up(x, off, 64);
        if (lane >= off) x += y;
    }
    if (lane == 63) ws2[wid] = x;
    __syncthreads();
    int incl = x + (wid > 0 ? ws2[0] : 0);
    if (threadIdx.x < nb) bsum[threadIdx.x] = incl;
}

// C: add block offsets; emit rowptr, cur (exclusive), dinv
__global__ __launch_bounds__(512)
void k_scanC(const int* __restrict__ deg, int* __restrict__ rowptr,
             const int* __restrict__ bsum, int* __restrict__ cur,
             float* __restrict__ dinv, int n) {
    const int i = blockIdx.x * 512 + threadIdx.x;
    if (i >= n) return;
    const int off = (blockIdx.x > 0) ? bsum[blockIdx.x - 1] : 0;
    const int d = deg[i];
    const int incl = rowptr[i + 1] + off;
    rowptr[i + 1] = incl;
    cur[i] = incl - d;
    dinv[i] = rsqrtf((float)(d + 1));   // +1 self-loop
    if (i == 0) rowptr[0] = 0;
}

__global__ void k_fill(const void* ei, const int* flag, int* cur, int* adj, int e) {
    int i = blockIdx.x * blockDim.x + threadIdx.x;
    if (i >= e) return;
    int is64 = *flag;
    int s = eload(ei, i, is64);
    int d = eload(ei, e + i, is64);
    int pos = atomicAdd(&cur[d], 1);
    adj[pos] = s;
}

// ---------------- weight transpose + split: Bt[n][k] = split(W[k][n]) -----
__global__ void k_splitT(const float* __restrict__ W, ushort* __restrict__ ohi,
                         ushort* __restrict__ olo, int R /*K*/, int C /*true N*/,
                         int Nout /*padded N*/) {
    int idx = blockIdx.x * blockDim.x + threadIdx.x;
    if (idx >= Nout * R) return;
    int n = idx / R;
    int k = idx - n * R;
    float v = (n < C) ? W[(size_t)k * C + n] : 0.0f;
    ushort hi = f2bf(v);
    ohi[idx] = hi;
    olo[idx] = f2bf(v - bf2f(hi));
}

// ---------------- pull aggregation, layer 1 (F=128) -> split bf16 --------
// 4 rows/block, 1 wave per row, float2 (8B) gathers
__global__ __launch_bounds__(256)
void k_pull128v(const int* __restrict__ rowptr, const int* __restrict__ adj,
                const float* __restrict__ dinv, const float* __restrict__ x,
                ushort* __restrict__ ohi, ushort* __restrict__ olo, int n) {
    const int i = blockIdx.x * 4 + (threadIdx.x >> 6);
    if (i >= n) return;
    const int lane = threadIdx.x & 63;
    const float2* x2 = (const float2*)x;
    const float di = dinv[i];
    float2 v = x2[(size_t)i * 64 + lane];
    float a0 = di * v.x, a1 = di * v.y;
    int j = rowptr[i];
    const int end = rowptr[i + 1];
    for (; j + 4 <= end; j += 4) {
        int s0 = adj[j], s1 = adj[j + 1], s2 = adj[j + 2], s3 = adj[j + 3];
        float w0 = dinv[s0], w1 = dinv[s1], w2 = dinv[s2], w3 = dinv[s3];
        float2 p0 = x2[(size_t)s0 * 64 + lane];
        float2 p1 = x2[(size_t)s1 * 64 + lane];
        float2 p2 = x2[(size_t)s2 * 64 + lane];
        float2 p3 = x2[(size_t)s3 * 64 + lane];
        a0 += w0 * p0.x + w1 * p1.x + w2 * p2.x + w3 * p3.x;
        a1 += w0 * p0.y + w1 * p1.y + w2 * p2.y + w3 * p3.y;
    }
    for (; j < end; ++j) {
        int s = adj[j];
        float w = dinv[s];
        float2 p = x2[(size_t)s * 64 + lane];
        a0 += w * p.x;
        a1 += w * p.y;
    }
    a0 *= di; a1 *= di;
    ushort h0 = f2bf(a0), h1 = f2bf(a1);
    ((unsigned*)ohi)[(size_t)i * 64 + lane] = (unsigned)h0 | ((unsigned)h1 << 16);
    ushort l0 = f2bf(a0 - bf2f(h0)), l1 = f2bf(a1 - bf2f(h1));
    ((unsigned*)olo)[(size_t)i * 64 + lane] = (unsigned)l0 | ((unsigned)l1 << 16);
}

// ---------------- pull aggregation, layer 2 (F=250, t bf16 ld=256) -------
// 4 rows/block, 1 wave per row, uint2 (8B = 4 bf16) gathers
__global__ __launch_bounds__(256)
void k_pull250v(const int* __restrict__ rowptr, const int* __restrict__ adj,
                const float* __restrict__ dinv, const ushort* __restrict__ t,
                const float* __restrict__ bias, float* __restrict__ out, int n) {
    const int i = blockIdx.x * 4 + (threadIdx.x >> 6);
    if (i >= n) return;
    const int lane = threadIdx.x & 63;
    const uint2* t2 = (const uint2*)t;   // [row][64] x uint2 (256 bf16, cols 250..255 = 0)
    uint2 u = t2[(size_t)i * 64 + lane];
    float a0 = bf2f_lo(u.x), a1 = bf2f_hi(u.x);
    float a2 = bf2f_lo(u.y), a3 = bf2f_hi(u.y);
    int j = rowptr[i];
    const int end = rowptr[i + 1];
    for (; j + 4 <= end; j += 4) {
        int s0 = adj[j], s1 = adj[j + 1], s2 = adj[j + 2], s3 = adj[j + 3];
        uint2 u0 = t2[(size_t)s0 * 64 + lane];
        uint2 u1 = t2[(size_t)s1 * 64 + lane];
        uint2 u2 = t2[(size_t)s2 * 64 + lane];
        uint2 u3 = t2[(size_t)s3 * 64 + lane];
        a0 += bf2f_lo(u0.x) + bf2f_lo(u1.x) + bf2f_lo(u2.x) + bf2f_lo(u3.x);
        a1 += bf2f_hi(u0.x) + bf2f_hi(u1.x) + bf2f_hi(u2.x) + bf2f_hi(u3.x);
        a2 += bf2f_lo(u0.y) + bf2f_lo(u1.y) + bf2f_lo(u2.y) + bf2f_lo(u3.y);
        a3 += bf2f_hi(u0.y) + bf2f_hi(u1.y) + bf2f_hi(u2.y) + bf2f_hi(u3.y);
    }
    for (; j < end; ++j) {
        uint2 us = t2[(size_t)adj[j] * 64 + lane];
        a0 += bf2f_lo(us.x); a1 += bf2f_hi(us.x);
        a2 += bf2f_lo(us.y); a3 += bf2f_hi(us.y);
    }
    const float d = dinv[i];
    const int c0 = lane * 4;
    if (lane < 62) {
        float2 b0 = *(const float2*)&bias[c0];
        float2 b1 = *(const float2*)&bias[c0 + 2];
        float2 o0, o1;
        o0.x = fmaxf(d * a0 + b0.x, 0.0f);
        o0.y = fmaxf(d * a1 + b0.y, 0.0f);
        o1.x = fmaxf(d * a2 + b1.x, 0.0f);
        o1.y = fmaxf(d * a3 + b1.y, 0.0f);
        *(float2*)&out[(size_t)i * 250 + c0] = o0;
        *(float2*)&out[(size_t)i * 250 + c0 + 2] = o1;
    } else if (lane == 62) {   // cols 248,249
        float2 b0 = *(const float2*)&bias[248];
        float2 o0;
        o0.x = fmaxf(d * a0 + b0.x, 0.0f);
        o0.y = fmaxf(d * a1 + b0.y, 0.0f);
        *(float2*)&out[(size_t)i * 250 + 248] = o0;
    }
}

// ---------------- split-bf16 MFMA GEMM, dbuf 2-phase, XCD swizzle --------
__device__ __forceinline__ void gl16(const ushort* g, ushort* l) {
    __builtin_amdgcn_global_load_lds((const __attribute__((address_space(1))) void*)g,
                                     (__attribute__((address_space(3))) void*)l,
                                     16, 0, 0);
}

template<int NA>
__global__ __launch_bounds__(256, NA == 1 ? 3 : 2)
void k_mfma(const ushort* __restrict__ Ahi, const ushort* __restrict__ Alo,
            const ushort* __restrict__ Bhi, const ushort* __restrict__ Blo,
            const float* __restrict__ bias, const float* __restrict__ rscale,
            ushort* __restrict__ outp, int M, int K, int ldc, int mode,
            int CX, int PY) {
    constexpr int NARR = NA + 2;
    __shared__ __align__(16) ushort smem[2 * NARR * 4128];

    // ---- XCD swizzle decode: a panel's CX col-blocks get ids ≡ same (mod 8)
    int id = blockIdx.x;
    const int gsz = CX * 8;
    const int nfull = (PY >> 3) * gsz;
    int bx, by;
    if (id < nfull) {
        int gg = id / gsz;
        int r  = id - gg * gsz;
        bx = r >> 3;
        by = gg * 8 + (r & 7);
    } else {
        int rem  = id - nfull;
        int pbase = (PY >> 3) << 3;
        int prem  = PY - pbase;
        by = pbase + rem % prem;
        bx = rem / prem;
    }
    const int brow = by * 128;
    const int bcol = bx * 128;

    const int tid  = threadIdx.x;
    const int lane = tid & 63;
    const int w    = tid >> 6;
    const int g    = lane >> 4;
    const int lr   = lane & 15;
    const int wm   = w >> 1, wn = w & 1;

    const ushort* srcs[NARR];
    if constexpr (NA == 2) { srcs[0] = Ahi; srcs[1] = Alo; srcs[2] = Bhi; srcs[3] = Blo; }
    else                   { srcs[0] = Ahi; srcs[1] = Bhi; srcs[2] = Blo; }

    auto STAGE = [&](ushort* buf, int k0) {
        #pragma unroll
        for (int a = 0; a < NARR; ++a) {
            const int rbase = (a < NA) ? brow : bcol;
            #pragma unroll
            for (int t2 = 0; t2 < 2; ++t2) {
                const int b  = w * 2 + t2;
                const int c  = b >> 1;
                const int r0 = (b & 1) * 64;
                gl16(srcs[a] + (size_t)(rbase + r0 + lane) * K + k0 + c * 8,
                     buf + a * 4128 + c * 1032 + r0 * 8);
            }
        }
    };

    f32x4 acc[4][4] = {};

    STAGE(smem, 0);
    __syncthreads();
    int cur = 0;

    for (int k0 = 0; k0 < K; k0 += 32) {
        ushort* rb = smem + cur * (NARR * 4128);
        if (k0 + 32 < K)
            STAGE(smem + (cur ^ 1) * (NARR * 4128), k0 + 32);

        bf16x8 af[NA][4], bhf[4], blf[4];
        #pragma unroll
        for (int i = 0; i < 4; ++i) {
            const int ao = g * 1032 + (wm * 64 + i * 16 + lr) * 8;
            #pragma unroll
            for (int a = 0; a < NA; ++a)
                af[a][i] = *(const bf16x8*)(rb + a * 4128 + ao);
            const int bo = g * 1032 + (wn * 64 + i * 16 + lr) * 8;
            bhf[i] = *(const bf16x8*)(rb + NA * 4128 + bo);
            blf[i] = *(const bf16x8*)(rb + (NA + 1) * 4128 + bo);
        }
        #pragma unroll
        for (int mt = 0; mt < 4; ++mt)
            #pragma unroll
            for (int nt = 0; nt < 4; ++nt) {
                acc[mt][nt] = __builtin_amdgcn_mfma_f32_16x16x32_bf16(bhf[nt], af[0][mt], acc[mt][nt], 0, 0, 0);
                if constexpr (NA == 2)
                    acc[mt][nt] = __builtin_amdgcn_mfma_f32_16x16x32_bf16(bhf[nt], af[1][mt], acc[mt][nt], 0, 0, 0);
                acc[mt][nt] = __builtin_amdgcn_mfma_f32_16x16x32_bf16(blf[nt], af[0][mt], acc[mt][nt], 0, 0, 0);
            }
        __syncthreads();
        cur ^= 1;
    }

    // ---- epilogue: row = brow+wm*64+mt*16+lr, cols = bcol+wn*64+nt*16+g*4+r
    #pragma unroll
    for (int mt = 0; mt < 4; ++mt) {
        const int gr = brow + wm * 64 + mt * 16 + lr;
        if (gr >= M) continue;
        const float rs = (mode == 0) ? rscale[gr] : 0.0f;
        #pragma unroll
        for (int nt = 0; nt < 4; ++nt) {
            const int gc0 = bcol + wn * 64 + nt * 16 + g * 4;
            float v0, v1, v2, v3;
            if (mode == 0) {
                v0 = acc[mt][nt][0] * rs; v1 = acc[mt][nt][1] * rs;
                v2 = acc[mt][nt][2] * rs; v3 = acc[mt][nt][3] * rs;
            } else {
                const float4 bv = *(const float4*)&bias[gc0];
                v0 = fmaxf(acc[mt][nt][0] + bv.x, 0.0f);
                v1 = fmaxf(acc[mt][nt][1] + bv.y, 0.0f);
                v2 = fmaxf(acc[mt][nt][2] + bv.z, 0.0f);
                v3 = fmaxf(acc[mt][nt][3] + bv.w, 0.0f);
            }
            uint2 pk;
            pk.x = (unsigned)f2bf(v0) | ((unsigned)f2bf(v1) << 16);
            pk.y = (unsigned)f2bf(v2) | ((unsigned)f2bf(v3) << 16);
            *(uint2*)(outp + (size_t)gr * ldc + gc0) = pk;
        }
    }
}

extern "C" void kernel_launch(void* const* d_in, const int* in_sizes, int n_in,
                              void* d_out, int out_size, void* d_ws, size_t ws_size,
                              hipStream_t stream) {
    const float* x  = (const float*)d_in[0];
    const void*  ei = d_in[1];
    const float* W1 = (const float*)d_in[2];
    const float* b1 = (const float*)d_in[3];
    const float* W2 = (const float*)d_in[4];
    const float* b2 = (const float*)d_in[5];
    float* out = (float*)d_out;

    const int N = N_NODES;
    const int E = in_sizes[1] / 2;
    const int MPAD = 50048;          // 391 * 128
    const int NSCB = (N + 511) / 512;   // 98 scan blocks

    // ---- workspace layout ----
    char* base = (char*)d_ws;
    int*   flag   = (int*)base;                        // 256 B slot
    int*   deg    = (int*)(base + 256);                // [51200]
    int*   rowptr = deg + 51200;
    int*   cur    = rowptr + 51200;
    float* dinv   = (float*)(cur + 51200);
    int*   bsum   = (int*)(dinv + 51200);              // [128]
    int*   adj    = bsum + 128;                        // [E]
    char*  p      = (char*)(adj + ((E + 63) & ~63));
    ushort* A1hi  = (ushort*)p;  p += (size_t)MPAD * 128 * 2;
    ushort* A1lo  = (ushort*)p;  p += (size_t)MPAD * 128 * 2;
    ushort* tbuf  = A1hi;        // [N][256] bf16 aliases A1 (dead after GEMM1)
    ushort* h1hi  = (ushort*)p;  p += (size_t)MPAD * 512 * 2;   // plain bf16
    ushort* Bt1hi = (ushort*)p;  p += 512 * 128 * 2;
    ushort* Bt1lo = (ushort*)p;  p += 512 * 128 * 2;
    ushort* Bt2hi = (ushort*)p;  p += 256 * 512 * 2;
    ushort* Bt2lo = (ushort*)p;  p += 256 * 512 * 2;

    // 1. CSR build + normalization
    k_detect<<<1, 1024, 0, stream>>>(ei, flag);
    hipMemsetAsync(deg, 0, (size_t)N * sizeof(int), stream);
    k_hist<<<(E + 255) / 256, 256, 0, stream>>>(ei, flag, deg, E);
    k_scanA<<<NSCB, 512, 0, stream>>>(deg, rowptr + 1, bsum, N);
    k_scanB<<<1, 128, 0, stream>>>(bsum, NSCB);
    k_scanC<<<NSCB, 512, 0, stream>>>(deg, rowptr, bsum, cur, dinv, N);
    k_fill<<<(E + 255) / 256, 256, 0, stream>>>(ei, flag, cur, adj, E);

    // 2. weight prep: transpose + split
    k_splitT<<<(512 * 128 + 255) / 256, 256, 0, stream>>>(W1, Bt1hi, Bt1lo, 128, 512, 512);
    k_splitT<<<(256 * 512 + 255) / 256, 256, 0, stream>>>(W2, Bt2hi, Bt2lo, 512, 250, 256);

    // 3. layer-1 aggregation -> A1 (split bf16)  [N,128]
    k_pull128v<<<(N + 3) / 4, 256, 0, stream>>>(rowptr, adj, dinv, x, A1hi, A1lo, N);

    // 4. h1 = relu(A1 @ W1 + b1) -> plain bf16 [N,512]   (NA=2, 3 products)
    k_mfma<2><<<4 * 391, 256, 0, stream>>>(A1hi, A1lo, Bt1hi, Bt1lo,
                                           b1, nullptr, h1hi,
                                           N, 128, 512, 1, 4, 391);

    // 5. t = bf16( dinv[row] * (h1 @ W2) )  [N,256]      (NA=1, 2 products)
    k_mfma<1><<<2 * 391, 256, 0, stream>>>(h1hi, nullptr, Bt2hi, Bt2lo,
                                           nullptr, dinv, tbuf,
                                           N, 512, 256, 0, 2, 391);

    // 6. layer-2 aggregation + bias + relu -> out  [N,250]
    k_pull250v<<<(N + 3) / 4, 256, 0, stream>>>(rowptr, adj, dinv, tbuf, b2, out, N);
}

// Round 7
// 317.543 us; speedup vs baseline: 6.2738x; 1.0931x over previous
//
#include <hip/hip_runtime.h>

#define N_NODES 50000

typedef __attribute__((ext_vector_type(8))) short bf16x8;
typedef __attribute__((ext_vector_type(4))) float f32x4;

__device__ __forceinline__ ushort f2bf(float f) {
    union { float f; unsigned u; } v; v.f = f;
    unsigned r = v.u + 0x7fff + ((v.u >> 16) & 1);   // round-to-nearest-even
    return (ushort)(r >> 16);
}
__device__ __forceinline__ float bf2f(ushort u) {
    union { unsigned u; float f; } v; v.u = ((unsigned)u) << 16;
    return v.f;
}
__device__ __forceinline__ float bf2f_lo(unsigned u) {
    union { unsigned u; float f; } v; v.u = u << 16;
    return v.f;
}
__device__ __forceinline__ float bf2f_hi(unsigned u) {
    union { unsigned u; float f; } v; v.u = u & 0xffff0000u;
    return v.f;
}

// ---------------- index-width detection (int64 vs int32 edge_index) --------
__global__ void k_detect(const void* ei, int* flag) {
    __shared__ int bad;
    if (threadIdx.x == 0) bad = 0;
    __syncthreads();
    long long v = ((const long long*)ei)[threadIdx.x];
    if (v < 0 || v >= N_NODES) atomicOr(&bad, 1);
    __syncthreads();
    if (threadIdx.x == 0) *flag = bad ? 0 : 1;
}

__device__ __forceinline__ int eload(const void* ei, int idx, int is64) {
    return is64 ? (int)((const long long*)ei)[idx] : ((const int*)ei)[idx];
}

// ---------------- CSR build ----------------
__global__ void k_hist(const void* ei, const int* flag, int* deg, int e) {
    int i = blockIdx.x * blockDim.x + threadIdx.x;
    if (i >= e) return;
    int is64 = *flag;
    int d = eload(ei, e + i, is64);
    atomicAdd(&deg[d], 1);
}

// ---- device-wide scan, 3 kernels ----
__global__ __launch_bounds__(512)
void k_scanA(const int* __restrict__ deg, int* __restrict__ rp1,
             int* __restrict__ bsum, int n) {
    __shared__ int wsum[8];
    const int i = blockIdx.x * 512 + threadIdx.x;
    const int lane = threadIdx.x & 63, wid = threadIdx.x >> 6;
    int x = (i < n) ? deg[i] : 0;
    #pragma unroll
    for (int off = 1; off < 64; off <<= 1) {
        int y = __shfl_up(x, off, 64);
        if (lane >= off) x += y;
    }
    if (lane == 63) wsum[wid] = x;
    __syncthreads();
    if (wid == 0 && lane < 8) {
        int s = wsum[lane];
        #pragma unroll
        for (int off = 1; off < 8; off <<= 1) {
            int y = __shfl_up(s, off, 64);
            if (lane >= off) s += y;
        }
        wsum[lane] = s;
    }
    __syncthreads();
    int incl = x + (wid > 0 ? wsum[wid - 1] : 0);
    if (i < n) rp1[i] = incl;
    if (threadIdx.x == 0) bsum[blockIdx.x] = wsum[7];
}

__global__ void k_scanB(int* bsum, int nb) {
    __shared__ int ws2[2];
    const int lane = threadIdx.x & 63, wid = threadIdx.x >> 6;
    int x = (threadIdx.x < nb) ? bsum[threadIdx.x] : 0;
    #pragma unroll
    for (int off = 1; off < 64; off <<= 1) {
        int y = __shfl_up(x, off, 64);
        if (lane >= off) x += y;
    }
    if (lane == 63) ws2[wid] = x;
    __syncthreads();
    int incl = x + (wid > 0 ? ws2[0] : 0);
    if (threadIdx.x < nb) bsum[threadIdx.x] = incl;
}

__global__ __launch_bounds__(512)
void k_scanC(const int* __restrict__ deg, int* __restrict__ rowptr,
             const int* __restrict__ bsum, int* __restrict__ cur,
             float* __restrict__ dinv, int n) {
    const int i = blockIdx.x * 512 + threadIdx.x;
    if (i >= n) return;
    const int off = (blockIdx.x > 0) ? bsum[blockIdx.x - 1] : 0;
    const int d = deg[i];
    const int incl = rowptr[i + 1] + off;
    rowptr[i + 1] = incl;
    cur[i] = incl - d;
    dinv[i] = rsqrtf((float)(d + 1));   // +1 self-loop
    if (i == 0) rowptr[0] = 0;
}

__global__ void k_fill(const void* ei, const int* flag, int* cur, int* adj, int e) {
    int i = blockIdx.x * blockDim.x + threadIdx.x;
    if (i >= e) return;
    int is64 = *flag;
    int s = eload(ei, i, is64);
    int d = eload(ei, e + i, is64);
    int pos = atomicAdd(&cur[d], 1);
    adj[pos] = s;
}

// ---------------- weight transpose + split: Bt[n][k] = split(W[k][n]) -----
__global__ void k_splitT(const float* __restrict__ W, ushort* __restrict__ ohi,
                         ushort* __restrict__ olo, int R /*K*/, int C /*true N*/,
                         int Nout /*padded N*/) {
    int idx = blockIdx.x * blockDim.x + threadIdx.x;
    if (idx >= Nout * R) return;
    int n = idx / R;
    int k = idx - n * R;
    float v = (n < C) ? W[(size_t)k * C + n] : 0.0f;
    ushort hi = f2bf(v);
    ohi[idx] = hi;
    olo[idx] = f2bf(v - bf2f(hi));
}

// ---------------- pull aggregation, layer 1 (F=128) -> bf16 --------------
// 4 rows/block, 1 wave per row, float2 (8B) gathers, 8-deep unroll
__global__ __launch_bounds__(256)
void k_pull128v(const int* __restrict__ rowptr, const int* __restrict__ adj,
                const float* __restrict__ dinv, const float* __restrict__ x,
                ushort* __restrict__ ohi, int n) {
    const int i = blockIdx.x * 4 + (threadIdx.x >> 6);
    if (i >= n) return;
    const int lane = threadIdx.x & 63;
    const float2* x2 = (const float2*)x;
    const float di = dinv[i];
    float2 v = x2[(size_t)i * 64 + lane];
    float a0 = di * v.x, a1 = di * v.y;
    int j = rowptr[i];
    const int end = rowptr[i + 1];
    for (; j + 8 <= end; j += 8) {
        int s0 = adj[j],     s1 = adj[j + 1], s2 = adj[j + 2], s3 = adj[j + 3];
        int s4 = adj[j + 4], s5 = adj[j + 5], s6 = adj[j + 6], s7 = adj[j + 7];
        float w0 = dinv[s0], w1 = dinv[s1], w2 = dinv[s2], w3 = dinv[s3];
        float w4 = dinv[s4], w5 = dinv[s5], w6 = dinv[s6], w7 = dinv[s7];
        float2 p0 = x2[(size_t)s0 * 64 + lane];
        float2 p1 = x2[(size_t)s1 * 64 + lane];
        float2 p2 = x2[(size_t)s2 * 64 + lane];
        float2 p3 = x2[(size_t)s3 * 64 + lane];
        float2 p4 = x2[(size_t)s4 * 64 + lane];
        float2 p5 = x2[(size_t)s5 * 64 + lane];
        float2 p6 = x2[(size_t)s6 * 64 + lane];
        float2 p7 = x2[(size_t)s7 * 64 + lane];
        a0 += w0 * p0.x + w1 * p1.x + w2 * p2.x + w3 * p3.x;
        a1 += w0 * p0.y + w1 * p1.y + w2 * p2.y + w3 * p3.y;
        a0 += w4 * p4.x + w5 * p5.x + w6 * p6.x + w7 * p7.x;
        a1 += w4 * p4.y + w5 * p5.y + w6 * p6.y + w7 * p7.y;
    }
    for (; j + 4 <= end; j += 4) {
        int s0 = adj[j], s1 = adj[j + 1], s2 = adj[j + 2], s3 = adj[j + 3];
        float w0 = dinv[s0], w1 = dinv[s1], w2 = dinv[s2], w3 = dinv[s3];
        float2 p0 = x2[(size_t)s0 * 64 + lane];
        float2 p1 = x2[(size_t)s1 * 64 + lane];
        float2 p2 = x2[(size_t)s2 * 64 + lane];
        float2 p3 = x2[(size_t)s3 * 64 + lane];
        a0 += w0 * p0.x + w1 * p1.x + w2 * p2.x + w3 * p3.x;
        a1 += w0 * p0.y + w1 * p1.y + w2 * p2.y + w3 * p3.y;
    }
    for (; j < end; ++j) {
        int s = adj[j];
        float w = dinv[s];
        float2 p = x2[(size_t)s * 64 + lane];
        a0 += w * p.x;
        a1 += w * p.y;
    }
    a0 *= di; a1 *= di;
    ((unsigned*)ohi)[(size_t)i * 64 + lane] =
        (unsigned)f2bf(a0) | ((unsigned)f2bf(a1) << 16);
}

// ---------------- pull aggregation, layer 2 (F=250, t bf16 ld=256) -------
// 4 rows/block, 1 wave per row, uint2 (8B = 4 bf16) gathers, 8-deep unroll
__global__ __launch_bounds__(256)
void k_pull250v(const int* __restrict__ rowptr, const int* __restrict__ adj,
                const float* __restrict__ dinv, const ushort* __restrict__ t,
                const float* __restrict__ bias, float* __restrict__ out, int n) {
    const int i = blockIdx.x * 4 + (threadIdx.x >> 6);
    if (i >= n) return;
    const int lane = threadIdx.x & 63;
    const uint2* t2 = (const uint2*)t;   // [row][64] x uint2 (256 bf16)
    uint2 u = t2[(size_t)i * 64 + lane];
    float a0 = bf2f_lo(u.x), a1 = bf2f_hi(u.x);
    float a2 = bf2f_lo(u.y), a3 = bf2f_hi(u.y);
    int j = rowptr[i];
    const int end = rowptr[i + 1];
    for (; j + 8 <= end; j += 8) {
        int s0 = adj[j],     s1 = adj[j + 1], s2 = adj[j + 2], s3 = adj[j + 3];
        int s4 = adj[j + 4], s5 = adj[j + 5], s6 = adj[j + 6], s7 = adj[j + 7];
        uint2 u0 = t2[(size_t)s0 * 64 + lane];
        uint2 u1 = t2[(size_t)s1 * 64 + lane];
        uint2 u2 = t2[(size_t)s2 * 64 + lane];
        uint2 u3 = t2[(size_t)s3 * 64 + lane];
        uint2 u4 = t2[(size_t)s4 * 64 + lane];
        uint2 u5 = t2[(size_t)s5 * 64 + lane];
        uint2 u6 = t2[(size_t)s6 * 64 + lane];
        uint2 u7 = t2[(size_t)s7 * 64 + lane];
        a0 += bf2f_lo(u0.x) + bf2f_lo(u1.x) + bf2f_lo(u2.x) + bf2f_lo(u3.x);
        a1 += bf2f_hi(u0.x) + bf2f_hi(u1.x) + bf2f_hi(u2.x) + bf2f_hi(u3.x);
        a2 += bf2f_lo(u0.y) + bf2f_lo(u1.y) + bf2f_lo(u2.y) + bf2f_lo(u3.y);
        a3 += bf2f_hi(u0.y) + bf2f_hi(u1.y) + bf2f_hi(u2.y) + bf2f_hi(u3.y);
        a0 += bf2f_lo(u4.x) + bf2f_lo(u5.x) + bf2f_lo(u6.x) + bf2f_lo(u7.x);
        a1 += bf2f_hi(u4.x) + bf2f_hi(u5.x) + bf2f_hi(u6.x) + bf2f_hi(u7.x);
        a2 += bf2f_lo(u4.y) + bf2f_lo(u5.y) + bf2f_lo(u6.y) + bf2f_lo(u7.y);
        a3 += bf2f_hi(u4.y) + bf2f_hi(u5.y) + bf2f_hi(u6.y) + bf2f_hi(u7.y);
    }
    for (; j + 4 <= end; j += 4) {
        int s0 = adj[j], s1 = adj[j + 1], s2 = adj[j + 2], s3 = adj[j + 3];
        uint2 u0 = t2[(size_t)s0 * 64 + lane];
        uint2 u1 = t2[(size_t)s1 * 64 + lane];
        uint2 u2 = t2[(size_t)s2 * 64 + lane];
        uint2 u3 = t2[(size_t)s3 * 64 + lane];
        a0 += bf2f_lo(u0.x) + bf2f_lo(u1.x) + bf2f_lo(u2.x) + bf2f_lo(u3.x);
        a1 += bf2f_hi(u0.x) + bf2f_hi(u1.x) + bf2f_hi(u2.x) + bf2f_hi(u3.x);
        a2 += bf2f_lo(u0.y) + bf2f_lo(u1.y) + bf2f_lo(u2.y) + bf2f_lo(u3.y);
        a3 += bf2f_hi(u0.y) + bf2f_hi(u1.y) + bf2f_hi(u2.y) + bf2f_hi(u3.y);
    }
    for (; j < end; ++j) {
        uint2 us = t2[(size_t)adj[j] * 64 + lane];
        a0 += bf2f_lo(us.x); a1 += bf2f_hi(us.x);
        a2 += bf2f_lo(us.y); a3 += bf2f_hi(us.y);
    }
    const float d = dinv[i];
    const int c0 = lane * 4;
    if (lane < 62) {
        float2 b0 = *(const float2*)&bias[c0];
        float2 b1 = *(const float2*)&bias[c0 + 2];
        float2 o0, o1;
        o0.x = fmaxf(d * a0 + b0.x, 0.0f);
        o0.y = fmaxf(d * a1 + b0.y, 0.0f);
        o1.x = fmaxf(d * a2 + b1.x, 0.0f);
        o1.y = fmaxf(d * a3 + b1.y, 0.0f);
        *(float2*)&out[(size_t)i * 250 + c0] = o0;
        *(float2*)&out[(size_t)i * 250 + c0 + 2] = o1;
    } else if (lane == 62) {   // cols 248,249
        float2 b0 = *(const float2*)&bias[248];
        float2 o0;
        o0.x = fmaxf(d * a0 + b0.x, 0.0f);
        o0.y = fmaxf(d * a1 + b0.y, 0.0f);
        *(float2*)&out[(size_t)i * 250 + 248] = o0;
    }
}

// ---------------- bf16 MFMA GEMM: C = A[MxK] @ Bt[N][K]^T ----------------
// A plain bf16; B split (Bhi,Blo). 2 MFMA products: a*bh + a*bl.
// Counted-vmcnt double-buffer: loads stay in flight across barriers.
// Swapped mfma operands -> lane holds 4 consecutive output cols.
// mode 0: out = bf16(acc * rscale[row]); mode 1: out = bf16(relu(acc+bias[col]))
__device__ __forceinline__ void gl16(const ushort* g, ushort* l) {
    __builtin_amdgcn_global_load_lds((const __attribute__((address_space(1))) void*)g,
                                     (__attribute__((address_space(3))) void*)l,
                                     16, 0, 0);
}

#define SMEM_HALF 12384   // 3 arrays * 4128 ushorts

__global__ __launch_bounds__(256, 3)
void k_mfma(const ushort* __restrict__ A, const ushort* __restrict__ Bhi,
            const ushort* __restrict__ Blo, const float* __restrict__ bias,
            const float* __restrict__ rscale, ushort* __restrict__ outp,
            int M, int K, int ldc, int mode, int CX, int PY) {
    __shared__ __align__(16) ushort smem[2 * SMEM_HALF];

    // ---- XCD swizzle decode: a panel's CX col-blocks get ids ≡ same (mod 8)
    int id = blockIdx.x;
    const int gsz = CX * 8;
    const int nfull = (PY >> 3) * gsz;
    int bx, by;
    if (id < nfull) {
        int gg = id / gsz;
        int r  = id - gg * gsz;
        bx = r >> 3;
        by = gg * 8 + (r & 7);
    } else {
        int rem  = id - nfull;
        int pbase = (PY >> 3) << 3;
        int prem  = PY - pbase;
        by = pbase + rem % prem;
        bx = rem / prem;
    }
    const int brow = by * 128;
    const int bcol = bx * 128;

    const int tid  = threadIdx.x;
    const int lane = tid & 63;
    const int w    = tid >> 6;
    const int g    = lane >> 4;
    const int lr   = lane & 15;
    const int wm   = w >> 1, wn = w & 1;

    const ushort* srcs[3] = {A, Bhi, Blo};

    auto STAGE = [&](ushort* buf, int k0) {
        #pragma unroll
        for (int a = 0; a < 3; ++a) {
            const int rbase = (a == 0) ? brow : bcol;
            #pragma unroll
            for (int t2 = 0; t2 < 2; ++t2) {
                const int b  = w * 2 + t2;
                const int c  = b >> 1;
                const int r0 = (b & 1) * 64;
                gl16(srcs[a] + (size_t)(rbase + r0 + lane) * K + k0 + c * 8,
                     buf + a * 4128 + c * 1032 + r0 * 8);
            }
        }
    };

    f32x4 acc[4][4] = {};

    auto COMPUTE = [&](const ushort* rb) {
        bf16x8 af[4], bhf[4], blf[4];
        #pragma unroll
        for (int i = 0; i < 4; ++i) {
            const int ao = g * 1032 + (wm * 64 + i * 16 + lr) * 8;
            af[i] = *(const bf16x8*)(rb + ao);
            const int bo = g * 1032 + (wn * 64 + i * 16 + lr) * 8;
            bhf[i] = *(const bf16x8*)(rb + 4128 + bo);
            blf[i] = *(const bf16x8*)(rb + 2 * 4128 + bo);
        }
        #pragma unroll
        for (int mt = 0; mt < 4; ++mt)
            #pragma unroll
            for (int nt = 0; nt < 4; ++nt) {
                acc[mt][nt] = __builtin_amdgcn_mfma_f32_16x16x32_bf16(bhf[nt], af[mt], acc[mt][nt], 0, 0, 0);
                acc[mt][nt] = __builtin_amdgcn_mfma_f32_16x16x32_bf16(blf[nt], af[mt], acc[mt][nt], 0, 0, 0);
            }
    };

    STAGE(smem, 0);
    int cur = 0;
    for (int k0 = 32; k0 < K; k0 += 32) {
        STAGE(smem + (cur ^ 1) * SMEM_HALF, k0);     // next tile in flight
        asm volatile("s_waitcnt vmcnt(6)" ::: "memory");  // own cur-tile loads done
        __builtin_amdgcn_sched_barrier(0);
        __builtin_amdgcn_s_barrier();                // all waves' cur-tile visible
        COMPUTE(smem + cur * SMEM_HALF);
        __builtin_amdgcn_sched_barrier(0);
        __builtin_amdgcn_s_barrier();                // WAR: reads done before restage
        cur ^= 1;
    }
    asm volatile("s_waitcnt vmcnt(0)" ::: "memory");
    __builtin_amdgcn_sched_barrier(0);
    __builtin_amdgcn_s_barrier();
    COMPUTE(smem + cur * SMEM_HALF);

    // ---- epilogue: row = brow+wm*64+mt*16+lr, cols = bcol+wn*64+nt*16+g*4+r
    #pragma unroll
    for (int mt = 0; mt < 4; ++mt) {
        const int gr = brow + wm * 64 + mt * 16 + lr;
        if (gr >= M) continue;
        const float rs = (mode == 0) ? rscale[gr] : 0.0f;
        #pragma unroll
        for (int nt = 0; nt < 4; ++nt) {
            const int gc0 = bcol + wn * 64 + nt * 16 + g * 4;
            float v0, v1, v2, v3;
            if (mode == 0) {
                v0 = acc[mt][nt][0] * rs; v1 = acc[mt][nt][1] * rs;
                v2 = acc[mt][nt][2] * rs; v3 = acc[mt][nt][3] * rs;
            } else {
                const float4 bv = *(const float4*)&bias[gc0];
                v0 = fmaxf(acc[mt][nt][0] + bv.x, 0.0f);
                v1 = fmaxf(acc[mt][nt][1] + bv.y, 0.0f);
                v2 = fmaxf(acc[mt][nt][2] + bv.z, 0.0f);
                v3 = fmaxf(acc[mt][nt][3] + bv.w, 0.0f);
            }
            uint2 pk;
            pk.x = (unsigned)f2bf(v0) | ((unsigned)f2bf(v1) << 16);
            pk.y = (unsigned)f2bf(v2) | ((unsigned)f2bf(v3) << 16);
            *(uint2*)(outp + (size_t)gr * ldc + gc0) = pk;
        }
    }
}

extern "C" void kernel_launch(void* const* d_in, const int* in_sizes, int n_in,
                              void* d_out, int out_size, void* d_ws, size_t ws_size,
                              hipStream_t stream) {
    const float* x  = (const float*)d_in[0];
    const void*  ei = d_in[1];
    const float* W1 = (const float*)d_in[2];
    const float* b1 = (const float*)d_in[3];
    const float* W2 = (const float*)d_in[4];
    const float* b2 = (const float*)d_in[5];
    float* out = (float*)d_out;

    const int N = N_NODES;
    const int E = in_sizes[1] / 2;
    const int MPAD = 50048;             // 391 * 128
    const int NSCB = (N + 511) / 512;   // 98 scan blocks

    // ---- workspace layout ----
    char* base = (char*)d_ws;
    int*   flag   = (int*)base;                        // 256 B slot
    int*   deg    = (int*)(base + 256);                // [51200]
    int*   rowptr = deg + 51200;
    int*   cur    = rowptr + 51200;
    float* dinv   = (float*)(cur + 51200);
    int*   bsum   = (int*)(dinv + 51200);              // [128]
    int*   adj    = bsum + 128;                        // [E]
    char*  p      = (char*)(adj + ((E + 63) & ~63));
    ushort* A1hi  = (ushort*)p;  p += (size_t)MPAD * 128 * 2;
    ushort* A1xx  = (ushort*)p;  p += (size_t)MPAD * 128 * 2;  // pad (tbuf tail)
    ushort* tbuf  = A1hi;        // [N][256] bf16, aliases A1hi+pad (dead after GEMM1)
    ushort* h1hi  = (ushort*)p;  p += (size_t)MPAD * 512 * 2;  // plain bf16
    ushort* Bt1hi = (ushort*)p;  p += 512 * 128 * 2;
    ushort* Bt1lo = (ushort*)p;  p += 512 * 128 * 2;
    ushort* Bt2hi = (ushort*)p;  p += 256 * 512 * 2;
    ushort* Bt2lo = (ushort*)p;  p += 256 * 512 * 2;
    (void)A1xx;

    // 1. CSR build + normalization
    k_detect<<<1, 1024, 0, stream>>>(ei, flag);
    hipMemsetAsync(deg, 0, (size_t)N * sizeof(int), stream);
    k_hist<<<(E + 255) / 256, 256, 0, stream>>>(ei, flag, deg, E);
    k_scanA<<<NSCB, 512, 0, stream>>>(deg, rowptr + 1, bsum, N);
    k_scanB<<<1, 128, 0, stream>>>(bsum, NSCB);
    k_scanC<<<NSCB, 512, 0, stream>>>(deg, rowptr, bsum, cur, dinv, N);
    k_fill<<<(E + 255) / 256, 256, 0, stream>>>(ei, flag, cur, adj, E);

    // 2. weight prep: transpose + split
    k_splitT<<<(512 * 128 + 255) / 256, 256, 0, stream>>>(W1, Bt1hi, Bt1lo, 128, 512, 512);
    k_splitT<<<(256 * 512 + 255) / 256, 256, 0, stream>>>(W2, Bt2hi, Bt2lo, 512, 250, 256);

    // 3. layer-1 aggregation -> A1 (bf16)  [N,128]
    k_pull128v<<<(N + 3) / 4, 256, 0, stream>>>(rowptr, adj, dinv, x, A1hi, N);

    // 4. h1 = relu(A1 @ W1 + b1) -> bf16 [N,512]
    k_mfma<<<4 * 391, 256, 0, stream>>>(A1hi, Bt1hi, Bt1lo, b1, nullptr, h1hi,
                                        N, 128, 512, 1, 4, 391);

    // 5. t = bf16( dinv[row] * (h1 @ W2) )  [N,256]
    k_mfma<<<2 * 391, 256, 0, stream>>>(h1hi, Bt2hi, Bt2lo, nullptr, dinv, tbuf,
                                        N, 512, 256, 0, 2, 391);

    // 6. layer-2 aggregation + bias + relu -> out  [N,250]
    k_pull250v<<<(N + 3) / 4, 256, 0, stream>>>(rowptr, adj, dinv, tbuf, b2, out, N);
}